// Round 6
// baseline (1074.134 us; speedup 1.0000x reference)
//
#include <hip/hip_runtime.h>
#include <hip/hip_bf16.h>
#include <stdint.h>

__device__ inline int imin(int a, int b) { return a < b ? a : b; }
__device__ inline int imax(int a, int b) { return a > b ? a : b; }
__device__ inline float bf2f(unsigned short u) {
    return __uint_as_float(((unsigned int)u) << 16);
}
// round-to-nearest-even fp32 -> bf16 bits
__device__ inline unsigned short f2bf(float v) {
    unsigned int u = __float_as_uint(v);
    unsigned int r = u + 0x7FFFu + ((u >> 16) & 1u);
    return (unsigned short)(r >> 16);
}

// intermediate storage: fp32 (preferred) or bf16 (small-ws fallback)
__device__ inline float ldv(const float* p) { return *p; }
__device__ inline float ldv(const unsigned short* p) { return bf2f(*p); }
__device__ inline void stv(float* p, float v) { *p = v; }
__device__ inline void stv(unsigned short* p, float v) { *p = f2bf(v); }

// ---------------- CSR build ----------------

__global__ void k_zero_i32(int* __restrict__ p, int n) {
    int i = blockIdx.x * blockDim.x + threadIdx.x;
    if (i < n) p[i] = 0;
}

__global__ void k_count(const int* __restrict__ col, int* __restrict__ cnt, int E, int n) {
    int e = blockIdx.x * blockDim.x + threadIdx.x;
    if (e < E) {
        int c = imax(0, imin(col[e], n - 1));
        atomicAdd(&cnt[c], 1);
    }
}

__global__ void k_dinv(const int* __restrict__ cnt, float* __restrict__ dinv, int n) {
    int i = blockIdx.x * blockDim.x + threadIdx.x;
    if (i < n) {
        float d = (float)imax(cnt[i], 0) + 1.0f;   // +1 self-loop; arg >= 1
        dinv[i] = rsqrtf(d);
    }
}

// single-block exclusive scan: offs/cursor = exclusive prefix sum of cnt
__global__ void k_scan_serial(const int* __restrict__ cnt, int* __restrict__ offs,
                              int* __restrict__ cursor, int n) {
    __shared__ int tmp[256];
    __shared__ int carry;
    if (threadIdx.x == 0) carry = 0;
    __syncthreads();
    for (int base = 0; base < n; base += 256) {
        int i = base + threadIdx.x;
        int v = (i < n) ? cnt[i] : 0;
        tmp[threadIdx.x] = v;
        __syncthreads();
        #pragma unroll
        for (int s = 1; s < 256; s <<= 1) {
            int t = (threadIdx.x >= s) ? tmp[threadIdx.x - s] : 0;
            __syncthreads();
            tmp[threadIdx.x] += t;
            __syncthreads();
        }
        int excl = carry + tmp[threadIdx.x] - v;
        if (i < n) { offs[i] = excl; cursor[i] = excl; }
        __syncthreads();
        if (threadIdx.x == 0) carry += tmp[255];
        __syncthreads();
    }
}

__global__ void k_fill(const int* __restrict__ row, const int* __restrict__ col,
                       int* __restrict__ cursor, int* __restrict__ csr_src,
                       int E, int n) {
    int e = blockIdx.x * blockDim.x + threadIdx.x;
    if (e >= E) return;
    int c = imax(0, imin(col[e], n - 1));
    int r = imax(0, imin(row[e], n - 1));
    int pos = atomicAdd(&cursor[c], 1);
    pos = imax(0, imin(pos, E - 1));
    csr_src[pos] = r;
}

// ---------------- GEMM: H = act @ W, all-fp32 math ----------------
// 32 rows/block, 256 threads. thread (rl=tid>>3, cg=tid&7): row rl, cols {32j+4cg+0..3}.

template <int FOUT, typename AT, typename HT>
__global__ __launch_bounds__(256) void k_gemm(const AT* __restrict__ act,
                                              const float* __restrict__ W,
                                              HT* __restrict__ H,
                                              int nrows, int Fin, int finShift) {
    constexpr int JMAX = FOUT / 32;
    __shared__ __align__(16) float sA[32 * 260];   // stride Fin+4, conflict-free
    __shared__ __align__(16) float sW[16 * FOUT];
    const int tid = threadIdx.x;
    const int row0 = blockIdx.x * 32;
    const int strA = Fin + 4;

    for (int i = tid; i < 32 * Fin; i += 256) {
        int r = i >> finShift;
        int k = i & (Fin - 1);
        float v = 0.f;
        if (row0 + r < nrows) v = ldv(&act[(size_t)row0 * Fin + i]);
        sA[r * strA + k] = v;
    }

    const int rl = tid >> 3;
    const int cg = tid & 7;
    float acc[JMAX][4];
    #pragma unroll
    for (int j = 0; j < JMAX; j++) {
        acc[j][0] = 0.f; acc[j][1] = 0.f; acc[j][2] = 0.f; acc[j][3] = 0.f;
    }

    for (int k0 = 0; k0 < Fin; k0 += 16) {
        __syncthreads();
        const float* wsrc = W + (size_t)k0 * FOUT;
        for (int i = tid; i < 16 * FOUT; i += 256) sW[i] = wsrc[i];
        __syncthreads();
        #pragma unroll 4
        for (int kk = 0; kk < 16; kk++) {
            float a = sA[rl * strA + k0 + kk];
            const float* wrow = &sW[kk * FOUT + cg * 4];
            #pragma unroll
            for (int j = 0; j < JMAX; j++) {
                float4 wv = *(const float4*)(wrow + j * 32);
                acc[j][0] = fmaf(a, wv.x, acc[j][0]);
                acc[j][1] = fmaf(a, wv.y, acc[j][1]);
                acc[j][2] = fmaf(a, wv.z, acc[j][2]);
                acc[j][3] = fmaf(a, wv.w, acc[j][3]);
            }
        }
    }

    const int rowi = row0 + rl;
    if (rowi < nrows) {
        #pragma unroll
        for (int j = 0; j < JMAX; j++) {
            HT* hp = &H[(size_t)rowi * FOUT + j * 32 + cg * 4];
            stv(hp + 0, acc[j][0]);
            stv(hp + 1, acc[j][1]);
            stv(hp + 2, acc[j][2]);
            stv(hp + 3, acc[j][3]);
        }
    }
}

// heads: Fout = 16; one thread per output element
template <typename AT, typename HT>
__global__ void k_gemm_small(const AT* __restrict__ act, const float* __restrict__ W,
                             HT* __restrict__ H, int nrows, int Fin) {
    int idx = blockIdx.x * blockDim.x + threadIdx.x;
    if (idx >= nrows * 16) return;
    int r = idx >> 4;
    int c = idx & 15;
    float acc = 0.f;
    for (int k = 0; k < Fin; k++)
        acc = fmaf(ldv(&act[(size_t)r * Fin + k]), W[k * 16 + c], acc);
    stv(&H[idx], acc);
}

// ---- aggregation: out = dinv[c]*(sum_e dinv[src]*H[src] + dinv[c]*H[c]) + b ----

template <int F, bool RELU, typename HT, typename OT>
__global__ __launch_bounds__(256) void k_agg(const HT* __restrict__ H,
                                             OT* __restrict__ out,
                                             const int* __restrict__ offs, const int* __restrict__ src,
                                             const float* __restrict__ dinv,
                                             const float* __restrict__ bias,
                                             int nnodes, int Etot) {
    constexpr int TPN = (F >= 64) ? 64 : F;   // threads per node
    constexpr int FPL = F / TPN;              // features per lane
    int t = blockIdx.x * 256 + threadIdx.x;
    int node = t / TPN;
    int ln = t % TPN;
    if (node >= nnodes) return;

    float di = dinv[node];
    float acc[FPL];
    #pragma unroll
    for (int j = 0; j < FPL; j++) acc[j] = di * ldv(&H[(size_t)node * F + ln + j * TPN]); // self-loop

    int s0 = offs[node];
    int s1 = (node + 1 < nnodes) ? offs[node + 1] : Etot;
    s0 = imax(0, imin(s0, Etot));
    s1 = imax(s0, imin(s1, Etot));
    for (int e = s0; e < s1; e++) {
        int sr = imax(0, imin(src[e], nnodes - 1));
        float we = dinv[sr];
        const HT* hp = &H[(size_t)sr * F + ln];
        #pragma unroll
        for (int j = 0; j < FPL; j++) acc[j] = fmaf(we, ldv(hp + j * TPN), acc[j]);
    }
    #pragma unroll
    for (int j = 0; j < FPL; j++) {
        float v = fmaf(di, acc[j], bias[ln + j * TPN]);
        if (RELU) v = fmaxf(v, 0.f);
        stv(&out[(size_t)node * F + ln + j * TPN], v);
    }
}

// ---------------- pipeline (templated on intermediate storage) ----------------

template <typename HT>
static void run_pipeline(void* const* d_in, void* d_out, void* d_ws,
                         int N, int E, hipStream_t stream) {
    const float* x = (const float*)d_in[0];
    const int* ei = (const int*)d_in[1];
    const float* W1 = (const float*)d_in[2];
    const float* b1 = (const float*)d_in[3];
    const float* W2 = (const float*)d_in[4];
    const float* b2 = (const float*)d_in[5];
    const float* W3 = (const float*)d_in[6];
    const float* b3 = (const float*)d_in[7];
    const float* W4 = (const float*)d_in[8];
    const float* b4 = (const float*)d_in[9];
    const float* Wmu = (const float*)d_in[10];
    const float* bmu = (const float*)d_in[11];
    const float* Wls = (const float*)d_in[12];
    const float* bls = (const float*)d_in[13];
    const int* row = ei;        // edge_index[0] = source
    const int* col = ei + E;    // edge_index[1] = target

    // workspace layout
    char* base = (char*)d_ws;
    HT* H   = (HT*)base;                                     // N*256 elems
    HT* act = H + (size_t)N * 256;                           // N*256 elems
    float* dinv = (float*)(act + (size_t)N * 256);           // N
    int* cnt     = (int*)(dinv + N);                         // N
    int* offs    = cnt + N;                                  // N
    int* cursor  = offs + N;                                 // N
    int* csr_src = cursor + N;                               // E

    k_zero_i32<<<(N + 255) / 256, 256, 0, stream>>>(cnt, N);
    k_count<<<(E + 255) / 256, 256, 0, stream>>>(col, cnt, E, N);
    k_dinv<<<(N + 255) / 256, 256, 0, stream>>>(cnt, dinv, N);
    k_scan_serial<<<1, 256, 0, stream>>>(cnt, offs, cursor, N);
    k_fill<<<(E + 255) / 256, 256, 0, stream>>>(row, col, cursor, csr_src, E, N);

    const int gemmGrid = (N + 31) / 32;
    // layer 1: 128 -> 256  (input = x, fp32, straight from d_in)
    k_gemm<256, float, HT><<<gemmGrid, 256, 0, stream>>>(x, W1, H, N, 128, 7);
    k_agg<256, true, HT, HT><<<((size_t)N * 64 + 255) / 256, 256, 0, stream>>>(H, act, offs, csr_src, dinv, b1, N, E);
    // layer 2: 256 -> 128
    k_gemm<128, HT, HT><<<gemmGrid, 256, 0, stream>>>(act, W2, H, N, 256, 8);
    k_agg<128, true, HT, HT><<<((size_t)N * 64 + 255) / 256, 256, 0, stream>>>(H, act, offs, csr_src, dinv, b2, N, E);
    // layer 3: 128 -> 64
    k_gemm<64, HT, HT><<<gemmGrid, 256, 0, stream>>>(act, W3, H, N, 128, 7);
    k_agg<64, true, HT, HT><<<((size_t)N * 64 + 255) / 256, 256, 0, stream>>>(H, act, offs, csr_src, dinv, b3, N, E);
    // layer 4: 64 -> 32
    k_gemm<32, HT, HT><<<gemmGrid, 256, 0, stream>>>(act, W4, H, N, 64, 6);
    k_agg<32, true, HT, HT><<<((size_t)N * 32 + 255) / 256, 256, 0, stream>>>(H, act, offs, csr_src, dinv, b4, N, E);
    // heads: 32 -> 16 (mu, logstd), no relu; h4 lives in act; OUTPUT IS FP32 (round-6 change)
    float* outF = (float*)d_out;
    k_gemm_small<HT, HT><<<((size_t)N * 16 + 255) / 256, 256, 0, stream>>>(act, Wmu, H, N, 32);
    k_agg<16, false, HT, float><<<((size_t)N * 16 + 255) / 256, 256, 0, stream>>>(H, outF, offs, csr_src, dinv, bmu, N, E);
    k_gemm_small<HT, HT><<<((size_t)N * 16 + 255) / 256, 256, 0, stream>>>(act, Wls, H, N, 32);
    k_agg<16, false, HT, float><<<((size_t)N * 16 + 255) / 256, 256, 0, stream>>>(H, outF + (size_t)N * 16, offs, csr_src, dinv, bls, N, E);
}

extern "C" void kernel_launch(void* const* d_in, const int* in_sizes, int n_in,
                              void* d_out, int out_size, void* d_ws, size_t ws_size,
                              hipStream_t stream) {
    const int N = in_sizes[0] / 128;
    const int E = in_sizes[1] / 2;

    // fp32 intermediates need: H + act (N*256*4 each) + dinv/cnt/offs/cursor (4N*4) + csr (E*4)
    size_t need_f32 = (size_t)N * 256 * 8 + (size_t)N * 16 + (size_t)E * 4;
    if (ws_size >= need_f32)
        run_pipeline<float>(d_in, d_out, d_ws, N, E, stream);
    else
        run_pipeline<unsigned short>(d_in, d_out, d_ws, N, E, stream);
}

// Round 7
// 875.806 us; speedup vs baseline: 1.2265x; 1.2265x over previous
//
#include <hip/hip_runtime.h>
#include <hip/hip_bf16.h>
#include <stdint.h>

__device__ inline int imin(int a, int b) { return a < b ? a : b; }
__device__ inline int imax(int a, int b) { return a > b ? a : b; }
__device__ inline float bf2f(unsigned short u) {
    return __uint_as_float(((unsigned int)u) << 16);
}
__device__ inline unsigned short f2bf(float v) {
    unsigned int u = __float_as_uint(v);
    unsigned int r = u + 0x7FFFu + ((u >> 16) & 1u);
    return (unsigned short)(r >> 16);
}

// intermediate storage: fp32 (preferred) or bf16 (small-ws fallback)
__device__ inline float ldv(const float* p) { return *p; }
__device__ inline float ldv(const unsigned short* p) { return bf2f(*p); }
__device__ inline void stv(float* p, float v) { *p = v; }
__device__ inline void stv(unsigned short* p, float v) { *p = f2bf(v); }

// ---------------- CSR build ----------------

__global__ void k_zero_i32(int* __restrict__ p, int n) {
    int i = blockIdx.x * blockDim.x + threadIdx.x;
    if (i < n) p[i] = 0;
}

__global__ void k_count(const int* __restrict__ col, int* __restrict__ cnt, int E, int n) {
    int e = blockIdx.x * blockDim.x + threadIdx.x;
    if (e < E) {
        int c = imax(0, imin(col[e], n - 1));
        atomicAdd(&cnt[c], 1);
    }
}

// pass 1: per-block exclusive scan of 256-elem tile; emit block sum
__global__ __launch_bounds__(256) void k_scan1(const int* __restrict__ cnt,
                                               int* __restrict__ partial,
                                               int* __restrict__ bsum, int n) {
    __shared__ int tmp[256];
    int i = blockIdx.x * 256 + threadIdx.x;
    int v = (i < n) ? cnt[i] : 0;
    tmp[threadIdx.x] = v;
    __syncthreads();
    #pragma unroll
    for (int s = 1; s < 256; s <<= 1) {
        int t = (threadIdx.x >= s) ? tmp[threadIdx.x - s] : 0;
        __syncthreads();
        tmp[threadIdx.x] += t;
        __syncthreads();
    }
    if (i < n) partial[i] = tmp[threadIdx.x] - v;       // exclusive within block
    if (threadIdx.x == 255) bsum[blockIdx.x] = tmp[255];
}

// pass 2: single block scans the block sums (nb <= a few hundred)
__global__ __launch_bounds__(256) void k_scan2(const int* __restrict__ bsum,
                                               int* __restrict__ bsumoff, int nb) {
    __shared__ int tmp[256];
    __shared__ int carry;
    if (threadIdx.x == 0) carry = 0;
    __syncthreads();
    for (int base = 0; base < nb; base += 256) {
        int i = base + threadIdx.x;
        int v = (i < nb) ? bsum[i] : 0;
        tmp[threadIdx.x] = v;
        __syncthreads();
        #pragma unroll
        for (int s = 1; s < 256; s <<= 1) {
            int t = (threadIdx.x >= s) ? tmp[threadIdx.x - s] : 0;
            __syncthreads();
            tmp[threadIdx.x] += t;
            __syncthreads();
        }
        if (i < nb) bsumoff[i] = carry + tmp[threadIdx.x] - v;
        __syncthreads();
        if (threadIdx.x == 0) carry += tmp[255];
        __syncthreads();
    }
}

// pass 3: uniform add -> offs & cursor; fused dinv compute
__global__ __launch_bounds__(256) void k_scan3(const int* __restrict__ partial,
                                               const int* __restrict__ bsumoff,
                                               const int* __restrict__ cnt,
                                               int* __restrict__ offs, int* __restrict__ cursor,
                                               float* __restrict__ dinv, int n) {
    int i = blockIdx.x * 256 + threadIdx.x;
    if (i >= n) return;
    int v = partial[i] + bsumoff[blockIdx.x];
    offs[i] = v;
    cursor[i] = v;
    float d = (float)imax(cnt[i], 0) + 1.0f;   // +1 self-loop
    dinv[i] = rsqrtf(d);
}

__global__ void k_fill(const int* __restrict__ row, const int* __restrict__ col,
                       int* __restrict__ cursor, int* __restrict__ csr_src,
                       int E, int n) {
    int e = blockIdx.x * blockDim.x + threadIdx.x;
    if (e >= E) return;
    int c = imax(0, imin(col[e], n - 1));
    int r = imax(0, imin(row[e], n - 1));
    int pos = atomicAdd(&cursor[c], 1);
    pos = imax(0, imin(pos, E - 1));
    csr_src[pos] = r;
}

// ---------------- GEMM: H = act @ W, all-fp32 math ----------------
// 32 rows/block, 256 threads. thread (rl=tid>>3, cg=tid&7): row rl, cols {32j+4cg+0..3}.

template <int FOUT, typename AT, typename HT>
__global__ __launch_bounds__(256) void k_gemm(const AT* __restrict__ act,
                                              const float* __restrict__ W,
                                              HT* __restrict__ H,
                                              int nrows, int Fin, int finShift) {
    constexpr int JMAX = FOUT / 32;
    __shared__ __align__(16) float sA[32 * 260];   // stride Fin+4, conflict-free
    __shared__ __align__(16) float sW[16 * FOUT];
    const int tid = threadIdx.x;
    const int row0 = blockIdx.x * 32;
    const int strA = Fin + 4;

    for (int i = tid; i < 32 * Fin; i += 256) {
        int r = i >> finShift;
        int k = i & (Fin - 1);
        float v = 0.f;
        if (row0 + r < nrows) v = ldv(&act[(size_t)row0 * Fin + i]);
        sA[r * strA + k] = v;
    }

    const int rl = tid >> 3;
    const int cg = tid & 7;
    float acc[JMAX][4];
    #pragma unroll
    for (int j = 0; j < JMAX; j++) {
        acc[j][0] = 0.f; acc[j][1] = 0.f; acc[j][2] = 0.f; acc[j][3] = 0.f;
    }

    for (int k0 = 0; k0 < Fin; k0 += 16) {
        __syncthreads();
        const float* wsrc = W + (size_t)k0 * FOUT;
        for (int i = tid; i < 16 * FOUT; i += 256) sW[i] = wsrc[i];
        __syncthreads();
        #pragma unroll 4
        for (int kk = 0; kk < 16; kk++) {
            float a = sA[rl * strA + k0 + kk];
            const float* wrow = &sW[kk * FOUT + cg * 4];
            #pragma unroll
            for (int j = 0; j < JMAX; j++) {
                float4 wv = *(const float4*)(wrow + j * 32);
                acc[j][0] = fmaf(a, wv.x, acc[j][0]);
                acc[j][1] = fmaf(a, wv.y, acc[j][1]);
                acc[j][2] = fmaf(a, wv.z, acc[j][2]);
                acc[j][3] = fmaf(a, wv.w, acc[j][3]);
            }
        }
    }

    const int rowi = row0 + rl;
    if (rowi < nrows) {
        #pragma unroll
        for (int j = 0; j < JMAX; j++) {
            HT* hp = &H[(size_t)rowi * FOUT + j * 32 + cg * 4];
            stv(hp + 0, acc[j][0]);
            stv(hp + 1, acc[j][1]);
            stv(hp + 2, acc[j][2]);
            stv(hp + 3, acc[j][3]);
        }
    }
}

// heads: Fout = 16; one thread per output element
template <typename AT, typename HT>
__global__ void k_gemm_small(const AT* __restrict__ act, const float* __restrict__ W,
                             HT* __restrict__ H, int nrows, int Fin) {
    int idx = blockIdx.x * blockDim.x + threadIdx.x;
    if (idx >= nrows * 16) return;
    int r = idx >> 4;
    int c = idx & 15;
    float acc = 0.f;
    for (int k = 0; k < Fin; k++)
        acc = fmaf(ldv(&act[(size_t)r * Fin + k]), W[k * 16 + c], acc);
    stv(&H[idx], acc);
}

// ---- aggregation: out = dinv[c]*(sum_e dinv[src]*H[src] + dinv[c]*H[c]) + b ----

template <int F, bool RELU, typename HT, typename OT>
__global__ __launch_bounds__(256) void k_agg(const HT* __restrict__ H,
                                             OT* __restrict__ out,
                                             const int* __restrict__ offs, const int* __restrict__ src,
                                             const float* __restrict__ dinv,
                                             const float* __restrict__ bias,
                                             int nnodes, int Etot) {
    constexpr int TPN = (F >= 64) ? 64 : F;   // threads per node
    constexpr int FPL = F / TPN;              // features per lane
    int t = blockIdx.x * 256 + threadIdx.x;
    int node = t / TPN;
    int ln = t % TPN;
    if (node >= nnodes) return;

    float di = dinv[node];
    float acc[FPL];
    #pragma unroll
    for (int j = 0; j < FPL; j++) acc[j] = di * ldv(&H[(size_t)node * F + ln + j * TPN]); // self-loop

    int s0 = offs[node];
    int s1 = (node + 1 < nnodes) ? offs[node + 1] : Etot;
    s0 = imax(0, imin(s0, Etot));
    s1 = imax(s0, imin(s1, Etot));
    for (int e = s0; e < s1; e++) {
        int sr = imax(0, imin(src[e], nnodes - 1));
        float we = dinv[sr];
        const HT* hp = &H[(size_t)sr * F + ln];
        #pragma unroll
        for (int j = 0; j < FPL; j++) acc[j] = fmaf(we, ldv(hp + j * TPN), acc[j]);
    }
    #pragma unroll
    for (int j = 0; j < FPL; j++) {
        float v = fmaf(di, acc[j], bias[ln + j * TPN]);
        if (RELU) v = fmaxf(v, 0.f);
        stv(&out[(size_t)node * F + ln + j * TPN], v);
    }
}

// ---------------- pipeline (templated on intermediate storage) ----------------

template <typename HT>
static void run_pipeline(void* const* d_in, void* d_out, void* d_ws,
                         int N, int E, hipStream_t stream) {
    const float* x = (const float*)d_in[0];
    const int* ei = (const int*)d_in[1];
    const float* W1 = (const float*)d_in[2];
    const float* b1 = (const float*)d_in[3];
    const float* W2 = (const float*)d_in[4];
    const float* b2 = (const float*)d_in[5];
    const float* W3 = (const float*)d_in[6];
    const float* b3 = (const float*)d_in[7];
    const float* W4 = (const float*)d_in[8];
    const float* b4 = (const float*)d_in[9];
    const float* Wmu = (const float*)d_in[10];
    const float* bmu = (const float*)d_in[11];
    const float* Wls = (const float*)d_in[12];
    const float* bls = (const float*)d_in[13];
    const int* row = ei;        // edge_index[0] = source
    const int* col = ei + E;    // edge_index[1] = target

    const int nb = (N + 255) / 256;

    // workspace layout
    char* base = (char*)d_ws;
    HT* H   = (HT*)base;                                     // N*256 elems
    HT* act = H + (size_t)N * 256;                           // N*256 elems
    float* dinv = (float*)(act + (size_t)N * 256);           // N
    int* cnt     = (int*)(dinv + N);                         // N
    int* offs    = cnt + N;                                  // N
    int* cursor  = offs + N;                                 // N
    int* partial = cursor + N;                               // N
    int* bsum    = partial + N;                              // nb
    int* bsumoff = bsum + nb;                                // nb
    int* csr_src = bsumoff + nb;                             // E

    k_zero_i32<<<nb, 256, 0, stream>>>(cnt, N);
    k_count<<<(E + 255) / 256, 256, 0, stream>>>(col, cnt, E, N);
    k_scan1<<<nb, 256, 0, stream>>>(cnt, partial, bsum, N);
    k_scan2<<<1, 256, 0, stream>>>(bsum, bsumoff, nb);
    k_scan3<<<nb, 256, 0, stream>>>(partial, bsumoff, cnt, offs, cursor, dinv, N);
    k_fill<<<(E + 255) / 256, 256, 0, stream>>>(row, col, cursor, csr_src, E, N);

    const int gemmGrid = (N + 31) / 32;
    // layer 1: 128 -> 256  (input = x, fp32, straight from d_in)
    k_gemm<256, float, HT><<<gemmGrid, 256, 0, stream>>>(x, W1, H, N, 128, 7);
    k_agg<256, true, HT, HT><<<((size_t)N * 64 + 255) / 256, 256, 0, stream>>>(H, act, offs, csr_src, dinv, b1, N, E);
    // layer 2: 256 -> 128
    k_gemm<128, HT, HT><<<gemmGrid, 256, 0, stream>>>(act, W2, H, N, 256, 8);
    k_agg<128, true, HT, HT><<<((size_t)N * 64 + 255) / 256, 256, 0, stream>>>(H, act, offs, csr_src, dinv, b2, N, E);
    // layer 3: 128 -> 64
    k_gemm<64, HT, HT><<<gemmGrid, 256, 0, stream>>>(act, W3, H, N, 128, 7);
    k_agg<64, true, HT, HT><<<((size_t)N * 64 + 255) / 256, 256, 0, stream>>>(H, act, offs, csr_src, dinv, b3, N, E);
    // layer 4: 64 -> 32
    k_gemm<32, HT, HT><<<gemmGrid, 256, 0, stream>>>(act, W4, H, N, 64, 6);
    k_agg<32, true, HT, HT><<<((size_t)N * 32 + 255) / 256, 256, 0, stream>>>(H, act, offs, csr_src, dinv, b4, N, E);
    // heads: 32 -> 16 (mu, logstd), no relu; h4 lives in act; fp32 out
    float* outF = (float*)d_out;
    k_gemm_small<HT, HT><<<((size_t)N * 16 + 255) / 256, 256, 0, stream>>>(act, Wmu, H, N, 32);
    k_agg<16, false, HT, float><<<((size_t)N * 16 + 255) / 256, 256, 0, stream>>>(H, outF, offs, csr_src, dinv, bmu, N, E);
    k_gemm_small<HT, HT><<<((size_t)N * 16 + 255) / 256, 256, 0, stream>>>(act, Wls, H, N, 32);
    k_agg<16, false, HT, float><<<((size_t)N * 16 + 255) / 256, 256, 0, stream>>>(H, outF + (size_t)N * 16, offs, csr_src, dinv, bls, N, E);
}

extern "C" void kernel_launch(void* const* d_in, const int* in_sizes, int n_in,
                              void* d_out, int out_size, void* d_ws, size_t ws_size,
                              hipStream_t stream) {
    const int N = in_sizes[0] / 128;
    const int E = in_sizes[1] / 2;
    const int nb = (N + 255) / 256;

    // fp32 tier: H+act (N*256*4 each) + dinv/cnt/offs/cursor/partial (5N*4) + 2nb*4 + csr (E*4)
    size_t need_f32 = (size_t)N * 256 * 8 + (size_t)N * 20 + (size_t)nb * 8 + (size_t)E * 4;
    if (ws_size >= need_f32)
        run_pipeline<float>(d_in, d_out, d_ws, N, E, stream);
    else
        run_pipeline<unsigned short>(d_in, d_out, d_ws, N, E, stream);
}

// Round 8
// 759.435 us; speedup vs baseline: 1.4144x; 1.1532x over previous
//
#include <hip/hip_runtime.h>
#include <hip/hip_bf16.h>
#include <stdint.h>

__device__ inline int imin(int a, int b) { return a < b ? a : b; }
__device__ inline int imax(int a, int b) { return a > b ? a : b; }
__device__ inline float bf2f(unsigned short u) {
    return __uint_as_float(((unsigned int)u) << 16);
}
__device__ inline unsigned short f2bf(float v) {
    unsigned int u = __float_as_uint(v);
    unsigned int r = u + 0x7FFFu + ((u >> 16) & 1u);
    return (unsigned short)(r >> 16);
}

// intermediate storage: fp32 (preferred) or bf16 (small-ws fallback)
__device__ inline float ldv(const float* p) { return *p; }
__device__ inline float ldv(const unsigned short* p) { return bf2f(*p); }
__device__ inline void stv(float* p, float v) { *p = v; }
__device__ inline void stv(unsigned short* p, float v) { *p = f2bf(v); }
__device__ inline float4 ld4(const float* p) { return *(const float4*)p; }
__device__ inline float4 ld4(const unsigned short* p) {
    ushort4 u = *(const ushort4*)p;
    return make_float4(bf2f(u.x), bf2f(u.y), bf2f(u.z), bf2f(u.w));
}

// ---------------- CSR build ----------------

__global__ void k_zero_i32(int* __restrict__ p, int n) {
    int i = blockIdx.x * blockDim.x + threadIdx.x;
    if (i < n) p[i] = 0;
}

__global__ void k_count(const int* __restrict__ col, int* __restrict__ cnt, int E, int n) {
    int e = blockIdx.x * blockDim.x + threadIdx.x;
    if (e < E) {
        int c = imax(0, imin(col[e], n - 1));
        atomicAdd(&cnt[c], 1);
    }
}

__global__ __launch_bounds__(256) void k_scan1(const int* __restrict__ cnt,
                                               int* __restrict__ partial,
                                               int* __restrict__ bsum, int n) {
    __shared__ int tmp[256];
    int i = blockIdx.x * 256 + threadIdx.x;
    int v = (i < n) ? cnt[i] : 0;
    tmp[threadIdx.x] = v;
    __syncthreads();
    #pragma unroll
    for (int s = 1; s < 256; s <<= 1) {
        int t = (threadIdx.x >= s) ? tmp[threadIdx.x - s] : 0;
        __syncthreads();
        tmp[threadIdx.x] += t;
        __syncthreads();
    }
    if (i < n) partial[i] = tmp[threadIdx.x] - v;
    if (threadIdx.x == 255) bsum[blockIdx.x] = tmp[255];
}

__global__ __launch_bounds__(256) void k_scan2(const int* __restrict__ bsum,
                                               int* __restrict__ bsumoff, int nb) {
    __shared__ int tmp[256];
    __shared__ int carry;
    if (threadIdx.x == 0) carry = 0;
    __syncthreads();
    for (int base = 0; base < nb; base += 256) {
        int i = base + threadIdx.x;
        int v = (i < nb) ? bsum[i] : 0;
        tmp[threadIdx.x] = v;
        __syncthreads();
        #pragma unroll
        for (int s = 1; s < 256; s <<= 1) {
            int t = (threadIdx.x >= s) ? tmp[threadIdx.x - s] : 0;
            __syncthreads();
            tmp[threadIdx.x] += t;
            __syncthreads();
        }
        if (i < nb) bsumoff[i] = carry + tmp[threadIdx.x] - v;
        __syncthreads();
        if (threadIdx.x == 0) carry += tmp[255];
        __syncthreads();
    }
}

__global__ __launch_bounds__(256) void k_scan3(const int* __restrict__ partial,
                                               const int* __restrict__ bsumoff,
                                               const int* __restrict__ cnt,
                                               int* __restrict__ offs, int* __restrict__ cursor,
                                               float* __restrict__ dinv, int n) {
    int i = blockIdx.x * 256 + threadIdx.x;
    if (i >= n) return;
    int v = partial[i] + bsumoff[blockIdx.x];
    offs[i] = v;
    cursor[i] = v;
    float d = (float)imax(cnt[i], 0) + 1.0f;
    dinv[i] = rsqrtf(d);
}

__global__ void k_fill(const int* __restrict__ row, const int* __restrict__ col,
                       int* __restrict__ cursor, int* __restrict__ csr_src,
                       int E, int n) {
    int e = blockIdx.x * blockDim.x + threadIdx.x;
    if (e >= E) return;
    int c = imax(0, imin(col[e], n - 1));
    int r = imax(0, imin(row[e], n - 1));
    int pos = atomicAdd(&cursor[c], 1);
    pos = imax(0, imin(pos, E - 1));
    csr_src[pos] = r;
}

// ---------------- GEMM v2: 64-row blocks, 4 rows x (FOUT/16) cols per thread ----------------
// thread (rg = tid>>4, cq = tid&15): rows rg*4..+3, cols {cq*4 + 64q : q < FOUT/64}.
// LDS: sA [k][row] pad-73 (a-reads conflict-free, broadcast x16);
//      sW flat [k][col] (reads 2-way aliased = free).

template <int FOUT, typename AT, typename HT>
__global__ __launch_bounds__(256) void k_gemm2(const AT* __restrict__ act,
                                               const float* __restrict__ W,
                                               HT* __restrict__ H,
                                               int nrows, int Fin) {
    constexpr int QN = FOUT / 64;              // float4 col-blocks per thread (256->4,128->2,64->1)
    __shared__ __align__(16) float sA[32 * 73];
    __shared__ __align__(16) float sW[32 * FOUT];
    const int tid = threadIdx.x;
    const int row0 = blockIdx.x * 64;
    const int rg = tid >> 4;                   // 0..15
    const int cq = tid & 15;                   // 0..15

    float4 acc[4][QN];
    #pragma unroll
    for (int i = 0; i < 4; i++)
        #pragma unroll
        for (int q = 0; q < QN; q++)
            acc[i][q] = make_float4(0.f, 0.f, 0.f, 0.f);

    const int rs = tid >> 3;                   // 0..31 (staging row)
    const int kq = (tid & 7) * 4;              // staging k quad

    for (int k0 = 0; k0 < Fin; k0 += 32) {
        __syncthreads();
        // stage A: 64 rows x 32 k, transposed into sA[k][row]
        #pragma unroll
        for (int half = 0; half < 2; half++) {
            int rr = rs + 32 * half;
            int grow = row0 + rr;
            float4 v = make_float4(0.f, 0.f, 0.f, 0.f);
            if (grow < nrows) v = ld4(&act[(size_t)grow * Fin + k0 + kq]);
            sA[(kq + 0) * 73 + rr] = v.x;
            sA[(kq + 1) * 73 + rr] = v.y;
            sA[(kq + 2) * 73 + rr] = v.z;
            sA[(kq + 3) * 73 + rr] = v.w;
        }
        // stage W: 32 x FOUT, flat float4 copy
        {
            const float4* wsrc = (const float4*)(W + (size_t)k0 * FOUT);
            float4* wdst = (float4*)sW;
            #pragma unroll
            for (int i = tid; i < 32 * FOUT / 4; i += 256) wdst[i] = wsrc[i];
        }
        __syncthreads();
        #pragma unroll 8
        for (int kk = 0; kk < 32; kk++) {
            const float a0 = sA[kk * 73 + rg * 4 + 0];
            const float a1 = sA[kk * 73 + rg * 4 + 1];
            const float a2 = sA[kk * 73 + rg * 4 + 2];
            const float a3 = sA[kk * 73 + rg * 4 + 3];
            #pragma unroll
            for (int q = 0; q < QN; q++) {
                float4 wv = *(const float4*)&sW[kk * FOUT + cq * 4 + 64 * q];
                acc[0][q].x = fmaf(a0, wv.x, acc[0][q].x);
                acc[0][q].y = fmaf(a0, wv.y, acc[0][q].y);
                acc[0][q].z = fmaf(a0, wv.z, acc[0][q].z);
                acc[0][q].w = fmaf(a0, wv.w, acc[0][q].w);
                acc[1][q].x = fmaf(a1, wv.x, acc[1][q].x);
                acc[1][q].y = fmaf(a1, wv.y, acc[1][q].y);
                acc[1][q].z = fmaf(a1, wv.z, acc[1][q].z);
                acc[1][q].w = fmaf(a1, wv.w, acc[1][q].w);
                acc[2][q].x = fmaf(a2, wv.x, acc[2][q].x);
                acc[2][q].y = fmaf(a2, wv.y, acc[2][q].y);
                acc[2][q].z = fmaf(a2, wv.z, acc[2][q].z);
                acc[2][q].w = fmaf(a2, wv.w, acc[2][q].w);
                acc[3][q].x = fmaf(a3, wv.x, acc[3][q].x);
                acc[3][q].y = fmaf(a3, wv.y, acc[3][q].y);
                acc[3][q].z = fmaf(a3, wv.z, acc[3][q].z);
                acc[3][q].w = fmaf(a3, wv.w, acc[3][q].w);
            }
        }
    }

    #pragma unroll
    for (int i = 0; i < 4; i++) {
        int grow = row0 + rg * 4 + i;
        if (grow < nrows) {
            #pragma unroll
            for (int q = 0; q < QN; q++) {
                HT* hp = &H[(size_t)grow * FOUT + cq * 4 + 64 * q];
                stv(hp + 0, acc[i][q].x);
                stv(hp + 1, acc[i][q].y);
                stv(hp + 2, acc[i][q].z);
                stv(hp + 3, acc[i][q].w);
            }
        }
    }
}

// ---------------- old GEMM (kept for FOUT=32) ----------------

template <int FOUT, typename AT, typename HT>
__global__ __launch_bounds__(256) void k_gemm(const AT* __restrict__ act,
                                              const float* __restrict__ W,
                                              HT* __restrict__ H,
                                              int nrows, int Fin, int finShift) {
    constexpr int JMAX = FOUT / 32;
    __shared__ __align__(16) float sA[32 * 260];
    __shared__ __align__(16) float sW[16 * FOUT];
    const int tid = threadIdx.x;
    const int row0 = blockIdx.x * 32;
    const int strA = Fin + 4;

    for (int i = tid; i < 32 * Fin; i += 256) {
        int r = i >> finShift;
        int k = i & (Fin - 1);
        float v = 0.f;
        if (row0 + r < nrows) v = ldv(&act[(size_t)row0 * Fin + i]);
        sA[r * strA + k] = v;
    }

    const int rl = tid >> 3;
    const int cg = tid & 7;
    float acc[JMAX][4];
    #pragma unroll
    for (int j = 0; j < JMAX; j++) {
        acc[j][0] = 0.f; acc[j][1] = 0.f; acc[j][2] = 0.f; acc[j][3] = 0.f;
    }

    for (int k0 = 0; k0 < Fin; k0 += 16) {
        __syncthreads();
        const float* wsrc = W + (size_t)k0 * FOUT;
        for (int i = tid; i < 16 * FOUT; i += 256) sW[i] = wsrc[i];
        __syncthreads();
        #pragma unroll 4
        for (int kk = 0; kk < 16; kk++) {
            float a = sA[rl * strA + k0 + kk];
            const float* wrow = &sW[kk * FOUT + cg * 4];
            #pragma unroll
            for (int j = 0; j < JMAX; j++) {
                float4 wv = *(const float4*)(wrow + j * 32);
                acc[j][0] = fmaf(a, wv.x, acc[j][0]);
                acc[j][1] = fmaf(a, wv.y, acc[j][1]);
                acc[j][2] = fmaf(a, wv.z, acc[j][2]);
                acc[j][3] = fmaf(a, wv.w, acc[j][3]);
            }
        }
    }

    const int rowi = row0 + rl;
    if (rowi < nrows) {
        #pragma unroll
        for (int j = 0; j < JMAX; j++) {
            HT* hp = &H[(size_t)rowi * FOUT + j * 32 + cg * 4];
            stv(hp + 0, acc[j][0]);
            stv(hp + 1, acc[j][1]);
            stv(hp + 2, acc[j][2]);
            stv(hp + 3, acc[j][3]);
        }
    }
}

// heads: Fout = 16; one thread per output element
template <typename AT, typename HT>
__global__ void k_gemm_small(const AT* __restrict__ act, const float* __restrict__ W,
                             HT* __restrict__ H, int nrows, int Fin) {
    int idx = blockIdx.x * blockDim.x + threadIdx.x;
    if (idx >= nrows * 16) return;
    int r = idx >> 4;
    int c = idx & 15;
    float acc = 0.f;
    for (int k = 0; k < Fin; k++)
        acc = fmaf(ldv(&act[(size_t)r * Fin + k]), W[k * 16 + c], acc);
    stv(&H[idx], acc);
}

// ---- aggregation: out = dinv[c]*(sum_e dinv[src]*H[src] + dinv[c]*H[c]) + b ----

template <int F, bool RELU, typename HT, typename OT>
__global__ __launch_bounds__(256) void k_agg(const HT* __restrict__ H,
                                             OT* __restrict__ out,
                                             const int* __restrict__ offs, const int* __restrict__ src,
                                             const float* __restrict__ dinv,
                                             const float* __restrict__ bias,
                                             int nnodes, int Etot) {
    constexpr int TPN = (F >= 64) ? 64 : F;
    constexpr int FPL = F / TPN;
    int t = blockIdx.x * 256 + threadIdx.x;
    int node = t / TPN;
    int ln = t % TPN;
    if (node >= nnodes) return;

    float di = dinv[node];
    float acc[FPL];
    #pragma unroll
    for (int j = 0; j < FPL; j++) acc[j] = di * ldv(&H[(size_t)node * F + ln + j * TPN]);

    int s0 = offs[node];
    int s1 = (node + 1 < nnodes) ? offs[node + 1] : Etot;
    s0 = imax(0, imin(s0, Etot));
    s1 = imax(s0, imin(s1, Etot));
    for (int e = s0; e < s1; e++) {
        int sr = imax(0, imin(src[e], nnodes - 1));
        float we = dinv[sr];
        const HT* hp = &H[(size_t)sr * F + ln];
        #pragma unroll
        for (int j = 0; j < FPL; j++) acc[j] = fmaf(we, ldv(hp + j * TPN), acc[j]);
    }
    #pragma unroll
    for (int j = 0; j < FPL; j++) {
        float v = fmaf(di, acc[j], bias[ln + j * TPN]);
        if (RELU) v = fmaxf(v, 0.f);
        stv(&out[(size_t)node * F + ln + j * TPN], v);
    }
}

// ---------------- pipeline ----------------

template <typename HT>
static void run_pipeline(void* const* d_in, void* d_out, void* d_ws,
                         int N, int E, hipStream_t stream) {
    const float* x = (const float*)d_in[0];
    const int* ei = (const int*)d_in[1];
    const float* W1 = (const float*)d_in[2];
    const float* b1 = (const float*)d_in[3];
    const float* W2 = (const float*)d_in[4];
    const float* b2 = (const float*)d_in[5];
    const float* W3 = (const float*)d_in[6];
    const float* b3 = (const float*)d_in[7];
    const float* W4 = (const float*)d_in[8];
    const float* b4 = (const float*)d_in[9];
    const float* Wmu = (const float*)d_in[10];
    const float* bmu = (const float*)d_in[11];
    const float* Wls = (const float*)d_in[12];
    const float* bls = (const float*)d_in[13];
    const int* row = ei;
    const int* col = ei + E;

    const int nb = (N + 255) / 256;

    char* base = (char*)d_ws;
    HT* H   = (HT*)base;                                     // N*256
    HT* act = H + (size_t)N * 256;                           // N*256
    float* dinv = (float*)(act + (size_t)N * 256);           // N
    int* cnt     = (int*)(dinv + N);
    int* offs    = cnt + N;
    int* cursor  = offs + N;
    int* partial = cursor + N;
    int* bsum    = partial + N;
    int* bsumoff = bsum + nb;
    int* csr_src = bsumoff + nb;                             // E

    k_zero_i32<<<nb, 256, 0, stream>>>(cnt, N);
    k_count<<<(E + 255) / 256, 256, 0, stream>>>(col, cnt, E, N);
    k_scan1<<<nb, 256, 0, stream>>>(cnt, partial, bsum, N);
    k_scan2<<<1, 256, 0, stream>>>(bsum, bsumoff, nb);
    k_scan3<<<nb, 256, 0, stream>>>(partial, bsumoff, cnt, offs, cursor, dinv, N);
    k_fill<<<(E + 255) / 256, 256, 0, stream>>>(row, col, cursor, csr_src, E, N);

    const int g64 = (N + 63) / 64;
    // layer 1: 128 -> 256
    k_gemm2<256, float, HT><<<g64, 256, 0, stream>>>(x, W1, H, N, 128);
    k_agg<256, true, HT, HT><<<((size_t)N * 64 + 255) / 256, 256, 0, stream>>>(H, act, offs, csr_src, dinv, b1, N, E);
    // layer 2: 256 -> 128
    k_gemm2<128, HT, HT><<<g64, 256, 0, stream>>>(act, W2, H, N, 256);
    k_agg<128, true, HT, HT><<<((size_t)N * 64 + 255) / 256, 256, 0, stream>>>(H, act, offs, csr_src, dinv, b2, N, E);
    // layer 3: 128 -> 64
    k_gemm2<64, HT, HT><<<g64, 256, 0, stream>>>(act, W3, H, N, 128);
    k_agg<64, true, HT, HT><<<((size_t)N * 64 + 255) / 256, 256, 0, stream>>>(H, act, offs, csr_src, dinv, b3, N, E);
    // layer 4: 64 -> 32
    k_gemm<32, HT, HT><<<(N + 31) / 32, 256, 0, stream>>>(act, W4, H, N, 64, 6);
    k_agg<32, true, HT, HT><<<((size_t)N * 32 + 255) / 256, 256, 0, stream>>>(H, act, offs, csr_src, dinv, b4, N, E);
    // heads: 32 -> 16, fp32 out
    float* outF = (float*)d_out;
    k_gemm_small<HT, HT><<<((size_t)N * 16 + 255) / 256, 256, 0, stream>>>(act, Wmu, H, N, 32);
    k_agg<16, false, HT, float><<<((size_t)N * 16 + 255) / 256, 256, 0, stream>>>(H, outF, offs, csr_src, dinv, bmu, N, E);
    k_gemm_small<HT, HT><<<((size_t)N * 16 + 255) / 256, 256, 0, stream>>>(act, Wls, H, N, 32);
    k_agg<16, false, HT, float><<<((size_t)N * 16 + 255) / 256, 256, 0, stream>>>(H, outF + (size_t)N * 16, offs, csr_src, dinv, bls, N, E);
}

extern "C" void kernel_launch(void* const* d_in, const int* in_sizes, int n_in,
                              void* d_out, int out_size, void* d_ws, size_t ws_size,
                              hipStream_t stream) {
    const int N = in_sizes[0] / 128;
    const int E = in_sizes[1] / 2;
    const int nb = (N + 255) / 256;

    size_t need_f32 = (size_t)N * 256 * 8 + (size_t)N * 20 + (size_t)nb * 8 + (size_t)E * 4;
    if (ws_size >= need_f32)
        run_pipeline<float>(d_in, d_out, d_ws, N, E, stream);
    else
        run_pipeline<unsigned short>(d_in, d_out, d_ws, N, E, stream);
}

// Round 9
// 639.131 us; speedup vs baseline: 1.6806x; 1.1882x over previous
//
#include <hip/hip_runtime.h>
#include <hip/hip_bf16.h>
#include <stdint.h>

__device__ inline int imin(int a, int b) { return a < b ? a : b; }
__device__ inline int imax(int a, int b) { return a > b ? a : b; }
__device__ inline float bf2f(unsigned short u) {
    return __uint_as_float(((unsigned int)u) << 16);
}
__device__ inline unsigned short f2bf(float v) {
    unsigned int u = __float_as_uint(v);
    unsigned int r = u + 0x7FFFu + ((u >> 16) & 1u);
    return (unsigned short)(r >> 16);
}
__device__ inline float4 ld4(const float* p) { return *(const float4*)p; }

// ---------------- CSR build ----------------

__global__ void k_zero_i32(int* __restrict__ p, int n) {
    int i = blockIdx.x * blockDim.x + threadIdx.x;
    if (i < n) p[i] = 0;
}

__global__ void k_count(const int* __restrict__ col, int* __restrict__ cnt, int E, int n) {
    int e = blockIdx.x * blockDim.x + threadIdx.x;
    if (e < E) {
        int c = imax(0, imin(col[e], n - 1));
        atomicAdd(&cnt[c], 1);
    }
}

__global__ __launch_bounds__(256) void k_scan1(const int* __restrict__ cnt,
                                               int* __restrict__ partial,
                                               int* __restrict__ bsum, int n) {
    __shared__ int tmp[256];
    int i = blockIdx.x * 256 + threadIdx.x;
    int v = (i < n) ? cnt[i] : 0;
    tmp[threadIdx.x] = v;
    __syncthreads();
    #pragma unroll
    for (int s = 1; s < 256; s <<= 1) {
        int t = (threadIdx.x >= s) ? tmp[threadIdx.x - s] : 0;
        __syncthreads();
        tmp[threadIdx.x] += t;
        __syncthreads();
    }
    if (i < n) partial[i] = tmp[threadIdx.x] - v;
    if (threadIdx.x == 255) bsum[blockIdx.x] = tmp[255];
}

__global__ __launch_bounds__(256) void k_scan2(const int* __restrict__ bsum,
                                               int* __restrict__ bsumoff, int nb) {
    __shared__ int tmp[256];
    __shared__ int carry;
    if (threadIdx.x == 0) carry = 0;
    __syncthreads();
    for (int base = 0; base < nb; base += 256) {
        int i = base + threadIdx.x;
        int v = (i < nb) ? bsum[i] : 0;
        tmp[threadIdx.x] = v;
        __syncthreads();
        #pragma unroll
        for (int s = 1; s < 256; s <<= 1) {
            int t = (threadIdx.x >= s) ? tmp[threadIdx.x - s] : 0;
            __syncthreads();
            tmp[threadIdx.x] += t;
            __syncthreads();
        }
        if (i < nb) bsumoff[i] = carry + tmp[threadIdx.x] - v;
        __syncthreads();
        if (threadIdx.x == 0) carry += tmp[255];
        __syncthreads();
    }
}

__global__ __launch_bounds__(256) void k_scan3(const int* __restrict__ partial,
                                               const int* __restrict__ bsumoff,
                                               const int* __restrict__ cnt,
                                               int* __restrict__ offs, int* __restrict__ cursor,
                                               float* __restrict__ dinv, int n) {
    int i = blockIdx.x * 256 + threadIdx.x;
    if (i >= n) return;
    int v = partial[i] + bsumoff[blockIdx.x];
    offs[i] = v;
    cursor[i] = v;
    float d = (float)imax(cnt[i], 0) + 1.0f;
    dinv[i] = rsqrtf(d);
}

__global__ void k_fill(const int* __restrict__ row, const int* __restrict__ col,
                       int* __restrict__ cursor, int* __restrict__ csr_src,
                       int E, int n) {
    int e = blockIdx.x * blockDim.x + threadIdx.x;
    if (e >= E) return;
    int c = imax(0, imin(col[e], n - 1));
    int r = imax(0, imin(row[e], n - 1));
    int pos = atomicAdd(&cursor[c], 1);
    pos = imax(0, imin(pos, E - 1));
    csr_src[pos] = r;
}

// ---------------- fp32 -> bf16 cast ----------------

__global__ void k_cvt_bf(const float* __restrict__ in, unsigned short* __restrict__ out, size_t n) {
    size_t i = (size_t)blockIdx.x * 256 + threadIdx.x;
    if (i < n) out[i] = f2bf(in[i]);
}

// ---------------- GEMM v2: 64-row blocks, 4 rows x (FOUT/16) cols per thread ----------------
// act fp32 in; out fp32 (EPI: +bias, relu) or bf16 (plain, for gathered H).

template <int FOUT, bool EPI, typename HT>
__global__ __launch_bounds__(256) void k_gemm2(const float* __restrict__ act,
                                               const float* __restrict__ W,
                                               HT* __restrict__ H,
                                               const float* __restrict__ bias,
                                               int nrows, int Fin) {
    constexpr int QN = FOUT / 64;
    __shared__ __align__(16) float sA[32 * 73];
    __shared__ __align__(16) float sW[32 * FOUT];
    const int tid = threadIdx.x;
    const int row0 = blockIdx.x * 64;
    const int rg = tid >> 4;
    const int cq = tid & 15;

    float4 acc[4][QN];
    #pragma unroll
    for (int i = 0; i < 4; i++)
        #pragma unroll
        for (int q = 0; q < QN; q++)
            acc[i][q] = make_float4(0.f, 0.f, 0.f, 0.f);

    const int rs = tid >> 3;
    const int kq = (tid & 7) * 4;

    for (int k0 = 0; k0 < Fin; k0 += 32) {
        __syncthreads();
        #pragma unroll
        for (int half = 0; half < 2; half++) {
            int rr = rs + 32 * half;
            int grow = row0 + rr;
            float4 v = make_float4(0.f, 0.f, 0.f, 0.f);
            if (grow < nrows) v = ld4(&act[(size_t)grow * Fin + k0 + kq]);
            sA[(kq + 0) * 73 + rr] = v.x;
            sA[(kq + 1) * 73 + rr] = v.y;
            sA[(kq + 2) * 73 + rr] = v.z;
            sA[(kq + 3) * 73 + rr] = v.w;
        }
        {
            const float4* wsrc = (const float4*)(W + (size_t)k0 * FOUT);
            float4* wdst = (float4*)sW;
            #pragma unroll
            for (int i = tid; i < 32 * FOUT / 4; i += 256) wdst[i] = wsrc[i];
        }
        __syncthreads();
        #pragma unroll 8
        for (int kk = 0; kk < 32; kk++) {
            const float a0 = sA[kk * 73 + rg * 4 + 0];
            const float a1 = sA[kk * 73 + rg * 4 + 1];
            const float a2 = sA[kk * 73 + rg * 4 + 2];
            const float a3 = sA[kk * 73 + rg * 4 + 3];
            #pragma unroll
            for (int q = 0; q < QN; q++) {
                float4 wv = *(const float4*)&sW[kk * FOUT + cq * 4 + 64 * q];
                acc[0][q].x = fmaf(a0, wv.x, acc[0][q].x);
                acc[0][q].y = fmaf(a0, wv.y, acc[0][q].y);
                acc[0][q].z = fmaf(a0, wv.z, acc[0][q].z);
                acc[0][q].w = fmaf(a0, wv.w, acc[0][q].w);
                acc[1][q].x = fmaf(a1, wv.x, acc[1][q].x);
                acc[1][q].y = fmaf(a1, wv.y, acc[1][q].y);
                acc[1][q].z = fmaf(a1, wv.z, acc[1][q].z);
                acc[1][q].w = fmaf(a1, wv.w, acc[1][q].w);
                acc[2][q].x = fmaf(a2, wv.x, acc[2][q].x);
                acc[2][q].y = fmaf(a2, wv.y, acc[2][q].y);
                acc[2][q].z = fmaf(a2, wv.z, acc[2][q].z);
                acc[2][q].w = fmaf(a2, wv.w, acc[2][q].w);
                acc[3][q].x = fmaf(a3, wv.x, acc[3][q].x);
                acc[3][q].y = fmaf(a3, wv.y, acc[3][q].y);
                acc[3][q].z = fmaf(a3, wv.z, acc[3][q].z);
                acc[3][q].w = fmaf(a3, wv.w, acc[3][q].w);
            }
        }
    }

    #pragma unroll
    for (int i = 0; i < 4; i++) {
        int grow = row0 + rg * 4 + i;
        if (grow < nrows) {
            #pragma unroll
            for (int q = 0; q < QN; q++) {
                int c0 = cq * 4 + 64 * q;
                float4 v = acc[i][q];
                if (EPI) {
                    v.x = fmaxf(v.x + bias[c0 + 0], 0.f);
                    v.y = fmaxf(v.y + bias[c0 + 1], 0.f);
                    v.z = fmaxf(v.z + bias[c0 + 2], 0.f);
                    v.w = fmaxf(v.w + bias[c0 + 3], 0.f);
                }
                HT* hp = &H[(size_t)grow * FOUT + c0];
                if (sizeof(HT) == 4) {
                    *(float4*)hp = v;
                } else {
                    unsigned short* up = (unsigned short*)hp;
                    up[0] = f2bf(v.x); up[1] = f2bf(v.y);
                    up[2] = f2bf(v.z); up[3] = f2bf(v.w);
                }
            }
        }
    }
}

// ---------------- small GEMMs ----------------

// FOUT=32, act fp32 -> H bf16
__global__ __launch_bounds__(256) void k_gemm32(const float* __restrict__ act,
                                                const float* __restrict__ W,
                                                unsigned short* __restrict__ H,
                                                int nrows, int Fin) {
    __shared__ __align__(16) float sA[32 * 68];    // stride Fin+4 = 68
    __shared__ __align__(16) float sW[16 * 32];
    const int tid = threadIdx.x;
    const int row0 = blockIdx.x * 32;
    const int strA = Fin + 4;

    for (int i = tid; i < 32 * Fin; i += 256) {
        int r = i >> 6;            // Fin = 64
        int k = i & 63;
        float v = 0.f;
        if (row0 + r < nrows) v = act[(size_t)row0 * Fin + i];
        sA[r * strA + k] = v;
    }

    const int rl = tid >> 3;
    const int cg = tid & 7;
    float a0 = 0.f, a1 = 0.f, a2 = 0.f, a3 = 0.f;

    for (int k0 = 0; k0 < Fin; k0 += 16) {
        __syncthreads();
        const float* wsrc = W + (size_t)k0 * 32;
        for (int i = tid; i < 16 * 32; i += 256) sW[i] = wsrc[i];
        __syncthreads();
        #pragma unroll 4
        for (int kk = 0; kk < 16; kk++) {
            float a = sA[rl * strA + k0 + kk];
            float4 wv = *(const float4*)&sW[kk * 32 + cg * 4];
            a0 = fmaf(a, wv.x, a0);
            a1 = fmaf(a, wv.y, a1);
            a2 = fmaf(a, wv.z, a2);
            a3 = fmaf(a, wv.w, a3);
        }
    }

    const int rowi = row0 + rl;
    if (rowi < nrows) {
        unsigned short* hp = &H[(size_t)rowi * 32 + cg * 4];
        hp[0] = f2bf(a0); hp[1] = f2bf(a1); hp[2] = f2bf(a2); hp[3] = f2bf(a3);
    }
}

// heads: Fout = 16, act fp32 -> H bf16
__global__ void k_gemm_small(const float* __restrict__ act, const float* __restrict__ W,
                             unsigned short* __restrict__ H, int nrows, int Fin) {
    int idx = blockIdx.x * blockDim.x + threadIdx.x;
    if (idx >= nrows * 16) return;
    int r = idx >> 4;
    int c = idx & 15;
    float acc = 0.f;
    for (int k = 0; k < Fin; k++)
        acc = fmaf(act[(size_t)r * Fin + k], W[k * 16 + c], acc);
    H[idx] = f2bf(acc);
}

// ---- aggregation over bf16 H: out = dinv[c]*(sum dinv[s]*H[s] + dinv[c]*H[c]) [+b] [relu], fp32 out ----
// 2 adjacent features per lane (ushort2 loads).

template <int F, bool RELU, bool HASBIAS>
__global__ __launch_bounds__(256) void k_aggb(const unsigned short* __restrict__ Hb,
                                              float* __restrict__ out,
                                              const int* __restrict__ offs, const int* __restrict__ src,
                                              const float* __restrict__ dinv,
                                              const float* __restrict__ bias,
                                              int nnodes, int Etot) {
    constexpr int TPN = (F >= 128) ? 64 : F / 2;   // lanes per node (2 feats each)
    int t = blockIdx.x * 256 + threadIdx.x;
    int node = t / TPN;
    int ln = t % TPN;
    if (node >= nnodes) return;
    int f0 = 2 * ln;

    float di = dinv[node];
    ushort2 sv = *(const ushort2*)&Hb[(size_t)node * F + f0];
    float acc0 = di * bf2f(sv.x);
    float acc1 = di * bf2f(sv.y);

    int s0 = offs[node];
    int s1 = (node + 1 < nnodes) ? offs[node + 1] : Etot;
    s0 = imax(0, imin(s0, Etot));
    s1 = imax(s0, imin(s1, Etot));
    for (int e = s0; e < s1; e++) {
        int sr = imax(0, imin(src[e], nnodes - 1));
        float we = dinv[sr];
        ushort2 hv = *(const ushort2*)&Hb[(size_t)sr * F + f0];
        acc0 = fmaf(we, bf2f(hv.x), acc0);
        acc1 = fmaf(we, bf2f(hv.y), acc1);
    }
    float v0 = di * acc0;
    float v1 = di * acc1;
    if (HASBIAS) { v0 += bias[f0]; v1 += bias[f0 + 1]; }
    if (RELU) { v0 = fmaxf(v0, 0.f); v1 = fmaxf(v1, 0.f); }
    *(float2*)&out[(size_t)node * F + f0] = make_float2(v0, v1);
}

// ---------------- pipeline ----------------

extern "C" void kernel_launch(void* const* d_in, const int* in_sizes, int n_in,
                              void* d_out, int out_size, void* d_ws, size_t ws_size,
                              hipStream_t stream) {
    const float* x = (const float*)d_in[0];
    const int* ei = (const int*)d_in[1];
    const float* W1 = (const float*)d_in[2];
    const float* b1 = (const float*)d_in[3];
    const float* W2 = (const float*)d_in[4];
    const float* b2 = (const float*)d_in[5];
    const float* W3 = (const float*)d_in[6];
    const float* b3 = (const float*)d_in[7];
    const float* W4 = (const float*)d_in[8];
    const float* b4 = (const float*)d_in[9];
    const float* Wmu = (const float*)d_in[10];
    const float* bmu = (const float*)d_in[11];
    const float* Wls = (const float*)d_in[12];
    const float* bls = (const float*)d_in[13];

    const int N = in_sizes[0] / 128;
    const int E = in_sizes[1] / 2;
    const int* row = ei;        // edge_index[0] = source
    const int* col = ei + E;    // edge_index[1] = target
    const int nb = (N + 255) / 256;

    // workspace: act(N*256 f32) | H(N*256 bf16) | xa(N*128 f32) | dinv,cnt,offs,cursor,partial | bsum,bsumoff | csr
    char* base = (char*)d_ws;
    float* act = (float*)base;                               // N*256 fp32
    unsigned short* H = (unsigned short*)(act + (size_t)N * 256);  // N*256 bf16
    unsigned short* xb = H;                                  // alias: x as bf16 (dead before H first write)
    float* xa = (float*)(H + (size_t)N * 256);               // N*128 fp32
    float* dinv = xa + (size_t)N * 128;                      // N
    int* cnt     = (int*)(dinv + N);
    int* offs    = cnt + N;
    int* cursor  = offs + N;
    int* partial = cursor + N;
    int* bsum    = partial + N;
    int* bsumoff = bsum + nb;
    int* csr_src = bsumoff + nb;                             // E

    // CSR + norms
    k_zero_i32<<<nb, 256, 0, stream>>>(cnt, N);
    k_count<<<(E + 255) / 256, 256, 0, stream>>>(col, cnt, E, N);
    k_scan1<<<nb, 256, 0, stream>>>(cnt, partial, bsum, N);
    k_scan2<<<1, 256, 0, stream>>>(bsum, bsumoff, nb);
    k_scan3<<<nb, 256, 0, stream>>>(partial, bsumoff, cnt, offs, cursor, dinv, N);
    k_fill<<<(E + 255) / 256, 256, 0, stream>>>(row, col, cursor, csr_src, E, N);

    const int g64 = (N + 63) / 64;
    // layer 1 restructured: act1 = relu( (Â x) W1 + b1 )
    k_cvt_bf<<<(unsigned)(((size_t)N * 128 + 255) / 256), 256, 0, stream>>>(x, xb, (size_t)N * 128);
    k_aggb<128, false, false><<<(unsigned)(((size_t)N * 64 + 255) / 256), 256, 0, stream>>>(xb, xa, offs, csr_src, dinv, nullptr, N, E);
    k_gemm2<256, true, float><<<g64, 256, 0, stream>>>(xa, W1, act, b1, N, 128);
    // layer 2: H2 = act1 @ W2 (bf16); act2 = relu(Â H2 + b2)
    k_gemm2<128, false, unsigned short><<<g64, 256, 0, stream>>>(act, W2, H, nullptr, N, 256);
    k_aggb<128, true, true><<<(unsigned)(((size_t)N * 64 + 255) / 256), 256, 0, stream>>>(H, act, offs, csr_src, dinv, b2, N, E);
    // layer 3: 128 -> 64
    k_gemm2<64, false, unsigned short><<<g64, 256, 0, stream>>>(act, W3, H, nullptr, N, 128);
    k_aggb<64, true, true><<<(unsigned)(((size_t)N * 32 + 255) / 256), 256, 0, stream>>>(H, act, offs, csr_src, dinv, b3, N, E);
    // layer 4: 64 -> 32
    k_gemm32<<<(N + 31) / 32, 256, 0, stream>>>(act, W4, H, N, 64);
    k_aggb<32, true, true><<<(unsigned)(((size_t)N * 16 + 255) / 256), 256, 0, stream>>>(H, act, offs, csr_src, dinv, b4, N, E);
    // heads: 32 -> 16, fp32 out to d_out (mu then logstd)
    float* outF = (float*)d_out;
    k_gemm_small<<<(unsigned)(((size_t)N * 16 + 255) / 256), 256, 0, stream>>>(act, Wmu, H, N, 32);
    k_aggb<16, false, true><<<(unsigned)(((size_t)N * 8 + 255) / 256), 256, 0, stream>>>(H, outF, offs, csr_src, dinv, bmu, N, E);
    k_gemm_small<<<(unsigned)(((size_t)N * 16 + 255) / 256), 256, 0, stream>>>(act, Wls, H, N, 32);
    k_aggb<16, false, true><<<(unsigned)(((size_t)N * 8 + 255) / 256), 256, 0, stream>>>(H, outF + (size_t)N * 16, offs, csr_src, dinv, bls, N, E);
}

// Round 10
// 484.711 us; speedup vs baseline: 2.2160x; 1.3186x over previous
//
#include <hip/hip_runtime.h>
#include <hip/hip_bf16.h>
#include <stdint.h>

__device__ inline int imin(int a, int b) { return a < b ? a : b; }
__device__ inline int imax(int a, int b) { return a > b ? a : b; }
__device__ inline float bf2f(unsigned short u) {
    return __uint_as_float(((unsigned int)u) << 16);
}
__device__ inline unsigned short f2bf(float v) {
    unsigned int u = __float_as_uint(v);
    unsigned int r = u + 0x7FFFu + ((u >> 16) & 1u);
    return (unsigned short)(r >> 16);
}
__device__ inline float4 ld4(const float* p) { return *(const float4*)p; }

// ---------------- CSR build (padded-to-4 segments) ----------------

__global__ void k_zero_i32(int* __restrict__ p, int n) {
    int i = blockIdx.x * blockDim.x + threadIdx.x;
    if (i < n) p[i] = 0;
}

__global__ void k_count(const int* __restrict__ col, int* __restrict__ cnt, int E, int n) {
    int e = blockIdx.x * blockDim.x + threadIdx.x;
    if (e < E) {
        int c = imax(0, imin(col[e], n - 1));
        atomicAdd(&cnt[c], 1);
    }
}

// scan over PAD4(cnt)
__global__ __launch_bounds__(256) void k_scan1(const int* __restrict__ cnt,
                                               int* __restrict__ partial,
                                               int* __restrict__ bsum, int n) {
    __shared__ int tmp[256];
    int i = blockIdx.x * 256 + threadIdx.x;
    int v = (i < n) ? ((cnt[i] + 3) & ~3) : 0;
    tmp[threadIdx.x] = v;
    __syncthreads();
    #pragma unroll
    for (int s = 1; s < 256; s <<= 1) {
        int t = (threadIdx.x >= s) ? tmp[threadIdx.x - s] : 0;
        __syncthreads();
        tmp[threadIdx.x] += t;
        __syncthreads();
    }
    if (i < n) partial[i] = tmp[threadIdx.x] - v;
    if (threadIdx.x == 255) bsum[blockIdx.x] = tmp[255];
}

__global__ __launch_bounds__(256) void k_scan2(const int* __restrict__ bsum,
                                               int* __restrict__ bsumoff, int nb) {
    __shared__ int tmp[256];
    __shared__ int carry;
    if (threadIdx.x == 0) carry = 0;
    __syncthreads();
    for (int base = 0; base < nb; base += 256) {
        int i = base + threadIdx.x;
        int v = (i < nb) ? bsum[i] : 0;
        tmp[threadIdx.x] = v;
        __syncthreads();
        #pragma unroll
        for (int s = 1; s < 256; s <<= 1) {
            int t = (threadIdx.x >= s) ? tmp[threadIdx.x - s] : 0;
            __syncthreads();
            tmp[threadIdx.x] += t;
            __syncthreads();
        }
        if (i < nb) bsumoff[i] = carry + tmp[threadIdx.x] - v;
        __syncthreads();
        if (threadIdx.x == 0) carry += tmp[255];
        __syncthreads();
    }
}

// offs has N+1 entries (offs[N] = total padded edges)
__global__ __launch_bounds__(256) void k_scan3(const int* __restrict__ partial,
                                               const int* __restrict__ bsumoff,
                                               const int* __restrict__ cnt,
                                               int* __restrict__ offs, int* __restrict__ cursor,
                                               float* __restrict__ dinv, int n) {
    int i = blockIdx.x * 256 + threadIdx.x;
    if (i >= n) return;
    int v = partial[i] + bsumoff[blockIdx.x];
    offs[i] = v;
    cursor[i] = v;
    if (i == n - 1) offs[n] = v + ((cnt[i] + 3) & ~3);
    float d = (float)imax(cnt[i], 0) + 1.0f;
    dinv[i] = rsqrtf(d);
}

// csr_w may be null (small-ws fallback)
__global__ void k_fill(const int* __restrict__ row, const int* __restrict__ col,
                       int* __restrict__ cursor, const float* __restrict__ dinv,
                       int* __restrict__ csr_src, float* __restrict__ csr_w,
                       int E, int n, int cap) {
    int e = blockIdx.x * blockDim.x + threadIdx.x;
    if (e >= E) return;
    int c = imax(0, imin(col[e], n - 1));
    int r = imax(0, imin(row[e], n - 1));
    int pos = atomicAdd(&cursor[c], 1);
    pos = imax(0, imin(pos, cap - 1));
    csr_src[pos] = r;
    if (csr_w) csr_w[pos] = dinv[r];
}

// fill pad slots [cursor[i], offs[i]+pad4(cnt[i])) with src=0, w=0
__global__ void k_pad(const int* __restrict__ cnt, const int* __restrict__ offs,
                      const int* __restrict__ cursor,
                      int* __restrict__ csr_src, float* __restrict__ csr_w, int n) {
    int i = blockIdx.x * blockDim.x + threadIdx.x;
    if (i >= n) return;
    int end = offs[i] + ((cnt[i] + 3) & ~3);
    for (int p = cursor[i]; p < end; p++) {
        csr_src[p] = 0;
        if (csr_w) csr_w[p] = 0.f;
    }
}

// ---------------- fp32 -> bf16 cast ----------------

__global__ void k_cvt_bf(const float* __restrict__ in, unsigned short* __restrict__ out, size_t n) {
    size_t i = (size_t)blockIdx.x * 256 + threadIdx.x;
    if (i < n) out[i] = f2bf(in[i]);
}

// ---------------- GEMM v2: 64-row blocks, 4 rows x (FOUT/16) cols per thread ----------------

template <int FOUT, bool EPI, typename HT>
__global__ __launch_bounds__(256) void k_gemm2(const float* __restrict__ act,
                                               const float* __restrict__ W,
                                               HT* __restrict__ H,
                                               const float* __restrict__ bias,
                                               int nrows, int Fin) {
    constexpr int QN = FOUT / 64;
    __shared__ __align__(16) float sA[32 * 73];
    __shared__ __align__(16) float sW[32 * FOUT];
    const int tid = threadIdx.x;
    const int row0 = blockIdx.x * 64;
    const int rg = tid >> 4;
    const int cq = tid & 15;

    float4 acc[4][QN];
    #pragma unroll
    for (int i = 0; i < 4; i++)
        #pragma unroll
        for (int q = 0; q < QN; q++)
            acc[i][q] = make_float4(0.f, 0.f, 0.f, 0.f);

    const int rs = tid >> 3;
    const int kq = (tid & 7) * 4;

    for (int k0 = 0; k0 < Fin; k0 += 32) {
        __syncthreads();
        #pragma unroll
        for (int half = 0; half < 2; half++) {
            int rr = rs + 32 * half;
            int grow = row0 + rr;
            float4 v = make_float4(0.f, 0.f, 0.f, 0.f);
            if (grow < nrows) v = ld4(&act[(size_t)grow * Fin + k0 + kq]);
            sA[(kq + 0) * 73 + rr] = v.x;
            sA[(kq + 1) * 73 + rr] = v.y;
            sA[(kq + 2) * 73 + rr] = v.z;
            sA[(kq + 3) * 73 + rr] = v.w;
        }
        {
            const float4* wsrc = (const float4*)(W + (size_t)k0 * FOUT);
            float4* wdst = (float4*)sW;
            #pragma unroll
            for (int i = tid; i < 32 * FOUT / 4; i += 256) wdst[i] = wsrc[i];
        }
        __syncthreads();
        #pragma unroll 8
        for (int kk = 0; kk < 32; kk++) {
            const float a0 = sA[kk * 73 + rg * 4 + 0];
            const float a1 = sA[kk * 73 + rg * 4 + 1];
            const float a2 = sA[kk * 73 + rg * 4 + 2];
            const float a3 = sA[kk * 73 + rg * 4 + 3];
            #pragma unroll
            for (int q = 0; q < QN; q++) {
                float4 wv = *(const float4*)&sW[kk * FOUT + cq * 4 + 64 * q];
                acc[0][q].x = fmaf(a0, wv.x, acc[0][q].x);
                acc[0][q].y = fmaf(a0, wv.y, acc[0][q].y);
                acc[0][q].z = fmaf(a0, wv.z, acc[0][q].z);
                acc[0][q].w = fmaf(a0, wv.w, acc[0][q].w);
                acc[1][q].x = fmaf(a1, wv.x, acc[1][q].x);
                acc[1][q].y = fmaf(a1, wv.y, acc[1][q].y);
                acc[1][q].z = fmaf(a1, wv.z, acc[1][q].z);
                acc[1][q].w = fmaf(a1, wv.w, acc[1][q].w);
                acc[2][q].x = fmaf(a2, wv.x, acc[2][q].x);
                acc[2][q].y = fmaf(a2, wv.y, acc[2][q].y);
                acc[2][q].z = fmaf(a2, wv.z, acc[2][q].z);
                acc[2][q].w = fmaf(a2, wv.w, acc[2][q].w);
                acc[3][q].x = fmaf(a3, wv.x, acc[3][q].x);
                acc[3][q].y = fmaf(a3, wv.y, acc[3][q].y);
                acc[3][q].z = fmaf(a3, wv.z, acc[3][q].z);
                acc[3][q].w = fmaf(a3, wv.w, acc[3][q].w);
            }
        }
    }

    #pragma unroll
    for (int i = 0; i < 4; i++) {
        int grow = row0 + rg * 4 + i;
        if (grow < nrows) {
            #pragma unroll
            for (int q = 0; q < QN; q++) {
                int c0 = cq * 4 + 64 * q;
                float4 v = acc[i][q];
                if (EPI) {
                    v.x = fmaxf(v.x + bias[c0 + 0], 0.f);
                    v.y = fmaxf(v.y + bias[c0 + 1], 0.f);
                    v.z = fmaxf(v.z + bias[c0 + 2], 0.f);
                    v.w = fmaxf(v.w + bias[c0 + 3], 0.f);
                }
                HT* hp = &H[(size_t)grow * FOUT + c0];
                if (sizeof(HT) == 4) {
                    *(float4*)hp = v;
                } else {
                    unsigned short* up = (unsigned short*)hp;
                    up[0] = f2bf(v.x); up[1] = f2bf(v.y);
                    up[2] = f2bf(v.z); up[3] = f2bf(v.w);
                }
            }
        }
    }
}

// FOUT=32, Fin=64, act fp32 -> H bf16
__global__ __launch_bounds__(256) void k_gemm32(const float* __restrict__ act,
                                                const float* __restrict__ W,
                                                unsigned short* __restrict__ H,
                                                int nrows) {
    __shared__ __align__(16) float sA[32 * 68];
    __shared__ __align__(16) float sW[16 * 32];
    const int tid = threadIdx.x;
    const int row0 = blockIdx.x * 32;
    const int Fin = 64, strA = 68;

    for (int i = tid; i < 32 * Fin; i += 256) {
        int r = i >> 6;
        int k = i & 63;
        float v = 0.f;
        if (row0 + r < nrows) v = act[(size_t)row0 * Fin + i];
        sA[r * strA + k] = v;
    }

    const int rl = tid >> 3;
    const int cg = tid & 7;
    float a0 = 0.f, a1 = 0.f, a2 = 0.f, a3 = 0.f;

    for (int k0 = 0; k0 < Fin; k0 += 16) {
        __syncthreads();
        const float* wsrc = W + (size_t)k0 * 32;
        for (int i = tid; i < 16 * 32; i += 256) sW[i] = wsrc[i];
        __syncthreads();
        #pragma unroll 4
        for (int kk = 0; kk < 16; kk++) {
            float a = sA[rl * strA + k0 + kk];
            float4 wv = *(const float4*)&sW[kk * 32 + cg * 4];
            a0 = fmaf(a, wv.x, a0);
            a1 = fmaf(a, wv.y, a1);
            a2 = fmaf(a, wv.z, a2);
            a3 = fmaf(a, wv.w, a3);
        }
    }

    const int rowi = row0 + rl;
    if (rowi < nrows) {
        unsigned short* hp = &H[(size_t)rowi * 32 + cg * 4];
        hp[0] = f2bf(a0); hp[1] = f2bf(a1); hp[2] = f2bf(a2); hp[3] = f2bf(a3);
    }
}

// combined heads GEMM: H[r][c] = act[r]·(c<16 ? Wmu[:,c] : Wls[:,c-16]); Fin=32
__global__ void k_gemm_heads(const float* __restrict__ act,
                             const float* __restrict__ Wmu, const float* __restrict__ Wls,
                             unsigned short* __restrict__ H, int nrows) {
    int idx = blockIdx.x * blockDim.x + threadIdx.x;
    if (idx >= nrows * 32) return;
    int r = idx >> 5;
    int c = idx & 31;
    const float* Wp = (c < 16) ? Wmu : Wls;
    int cc = c & 15;
    float acc = 0.f;
    #pragma unroll 8
    for (int k = 0; k < 32; k++)
        acc = fmaf(act[(size_t)r * 32 + k], Wp[k * 16 + cc], acc);
    H[idx] = f2bf(acc);
}

// ---- aggregation over bf16 H, 4x-unrolled padded CSR ----
// out = dinv[c]*(sum_e w_e*H[src_e] + dinv[c]*H[c]) [+b] [relu], fp32 out
// USEW: weights precomputed in csr_w; else load dinv[src] in-loop.

template <int F, bool RELU, bool HASBIAS, bool USEW>
__global__ __launch_bounds__(256) void k_aggb(const unsigned short* __restrict__ Hb,
                                              float* __restrict__ out,
                                              const int* __restrict__ offs, const int* __restrict__ src,
                                              const float* __restrict__ w,
                                              const float* __restrict__ dinv,
                                              const float* __restrict__ bias,
                                              int nnodes, int Ecap) {
    constexpr int TPN = (F >= 128) ? 64 : F / 2;
    int t = blockIdx.x * 256 + threadIdx.x;
    int node = t / TPN;
    int ln = t % TPN;
    if (node >= nnodes) return;
    int f0 = 2 * ln;

    float di = dinv[node];
    ushort2 sv = *(const ushort2*)&Hb[(size_t)node * F + f0];
    float acc0 = di * bf2f(sv.x);
    float acc1 = di * bf2f(sv.y);

    int s0 = offs[node];
    int s1 = offs[node + 1];
    s0 = imax(0, imin(s0, Ecap));
    s1 = imax(s0, imin(s1, Ecap));
    for (int e = s0; e < s1; e += 4) {
        const int4 sr4 = *(const int4*)(src + e);
        float w0, w1, w2, w3;
        if (USEW) {
            const float4 w4 = *(const float4*)(w + e);
            w0 = w4.x; w1 = w4.y; w2 = w4.z; w3 = w4.w;
        } else {
            w0 = dinv[sr4.x]; w1 = dinv[sr4.y]; w2 = dinv[sr4.z]; w3 = dinv[sr4.w];
        }
        ushort2 h0 = *(const ushort2*)&Hb[(size_t)sr4.x * F + f0];
        ushort2 h1 = *(const ushort2*)&Hb[(size_t)sr4.y * F + f0];
        ushort2 h2 = *(const ushort2*)&Hb[(size_t)sr4.z * F + f0];
        ushort2 h3 = *(const ushort2*)&Hb[(size_t)sr4.w * F + f0];
        acc0 = fmaf(w0, bf2f(h0.x), acc0);
        acc1 = fmaf(w0, bf2f(h0.y), acc1);
        acc0 = fmaf(w1, bf2f(h1.x), acc0);
        acc1 = fmaf(w1, bf2f(h1.y), acc1);
        acc0 = fmaf(w2, bf2f(h2.x), acc0);
        acc1 = fmaf(w2, bf2f(h2.y), acc1);
        acc0 = fmaf(w3, bf2f(h3.x), acc0);
        acc1 = fmaf(w3, bf2f(h3.y), acc1);
    }
    float v0 = di * acc0;
    float v1 = di * acc1;
    if (HASBIAS) { v0 += bias[f0]; v1 += bias[f0 + 1]; }
    if (RELU) { v0 = fmaxf(v0, 0.f); v1 = fmaxf(v1, 0.f); }
    *(float2*)&out[(size_t)node * F + f0] = make_float2(v0, v1);
}

// fused heads aggregation: F=32 (mu cols 0..15, logstd 16..31), split output
template <bool USEW>
__global__ __launch_bounds__(256) void k_agg_heads(const unsigned short* __restrict__ Hb,
                                                   float* __restrict__ out,
                                                   const int* __restrict__ offs, const int* __restrict__ src,
                                                   const float* __restrict__ w,
                                                   const float* __restrict__ dinv,
                                                   const float* __restrict__ bmu, const float* __restrict__ bls,
                                                   int nnodes, int Ecap) {
    constexpr int F = 32, TPN = 16;
    int t = blockIdx.x * 256 + threadIdx.x;
    int node = t / TPN;
    int ln = t % TPN;
    if (node >= nnodes) return;
    int f0 = 2 * ln;

    float di = dinv[node];
    ushort2 sv = *(const ushort2*)&Hb[(size_t)node * F + f0];
    float acc0 = di * bf2f(sv.x);
    float acc1 = di * bf2f(sv.y);

    int s0 = offs[node];
    int s1 = offs[node + 1];
    s0 = imax(0, imin(s0, Ecap));
    s1 = imax(s0, imin(s1, Ecap));
    for (int e = s0; e < s1; e += 4) {
        const int4 sr4 = *(const int4*)(src + e);
        float w0, w1, w2, w3;
        if (USEW) {
            const float4 w4 = *(const float4*)(w + e);
            w0 = w4.x; w1 = w4.y; w2 = w4.z; w3 = w4.w;
        } else {
            w0 = dinv[sr4.x]; w1 = dinv[sr4.y]; w2 = dinv[sr4.z]; w3 = dinv[sr4.w];
        }
        ushort2 h0 = *(const ushort2*)&Hb[(size_t)sr4.x * F + f0];
        ushort2 h1 = *(const ushort2*)&Hb[(size_t)sr4.y * F + f0];
        ushort2 h2 = *(const ushort2*)&Hb[(size_t)sr4.z * F + f0];
        ushort2 h3 = *(const ushort2*)&Hb[(size_t)sr4.w * F + f0];
        acc0 = fmaf(w0, bf2f(h0.x), acc0);
        acc1 = fmaf(w0, bf2f(h0.y), acc1);
        acc0 = fmaf(w1, bf2f(h1.x), acc0);
        acc1 = fmaf(w1, bf2f(h1.y), acc1);
        acc0 = fmaf(w2, bf2f(h2.x), acc0);
        acc1 = fmaf(w2, bf2f(h2.y), acc1);
        acc0 = fmaf(w3, bf2f(h3.x), acc0);
        acc1 = fmaf(w3, bf2f(h3.y), acc1);
    }
    const float* bp = (f0 < 16) ? bmu : bls;
    int fb = f0 & 15;
    float v0 = fmaf(di, acc0, bp[fb]);
    float v1 = fmaf(di, acc1, bp[fb + 1]);
    float* op = (f0 < 16) ? (out + (size_t)node * 16 + fb)
                          : (out + (size_t)nnodes * 16 + (size_t)node * 16 + fb);
    *(float2*)op = make_float2(v0, v1);
}

// ---------------- pipeline ----------------

template <bool USEW>
static void run_pipeline(void* const* d_in, void* d_out, void* d_ws,
                         int N, int E, hipStream_t stream) {
    const float* x  = (const float*)d_in[0];
    const int* ei   = (const int*)d_in[1];
    const float* W1 = (const float*)d_in[2];
    const float* b1 = (const float*)d_in[3];
    const float* W2 = (const float*)d_in[4];
    const float* b2 = (const float*)d_in[5];
    const float* W3 = (const float*)d_in[6];
    const float* b3 = (const float*)d_in[7];
    const float* W4 = (const float*)d_in[8];
    const float* b4 = (const float*)d_in[9];
    const float* Wmu = (const float*)d_in[10];
    const float* bmu = (const float*)d_in[11];
    const float* Wls = (const float*)d_in[12];
    const float* bls = (const float*)d_in[13];
    const int* row = ei;        // edge_index[0] = source
    const int* col = ei + E;    // edge_index[1] = target
    const int nb = (N + 255) / 256;
    const int E4 = E + 4 * N;   // capacity with padding

    auto align16 = [](char* p) {
        return (char*)(((uintptr_t)p + 15) & ~(uintptr_t)15);
    };
    char* p = (char*)d_ws;
    float* act = (float*)p;                      p += (size_t)N * 256 * 4;
    unsigned short* H = (unsigned short*)p;      p += (size_t)N * 256 * 2;
    unsigned short* xb = H;                      // alias (dead before H first write)
    float* xa = (float*)p;                       p += (size_t)N * 128 * 4;
    float* dinv = (float*)p;                     p += (size_t)N * 4;
    int* cnt = (int*)p;                          p += (size_t)N * 4;
    int* offs = (int*)p;                         p += (size_t)(N + 1) * 4;
    int* cursor = (int*)p;                       p += (size_t)N * 4;
    int* partial = (int*)p;                      p += (size_t)N * 4;
    int* bsum = (int*)p;                         p += (size_t)nb * 4;
    int* bsumoff = (int*)p;                      p += (size_t)nb * 4;
    p = align16(p);
    int* csr_src = (int*)p;                      p += (size_t)E4 * 4;
    p = align16(p);
    float* csr_w = USEW ? (float*)p : nullptr;

    // CSR + norms
    k_zero_i32<<<nb, 256, 0, stream>>>(cnt, N);
    k_count<<<(E + 255) / 256, 256, 0, stream>>>(col, cnt, E, N);
    k_scan1<<<nb, 256, 0, stream>>>(cnt, partial, bsum, N);
    k_scan2<<<1, 256, 0, stream>>>(bsum, bsumoff, nb);
    k_scan3<<<nb, 256, 0, stream>>>(partial, bsumoff, cnt, offs, cursor, dinv, N);
    k_fill<<<(E + 255) / 256, 256, 0, stream>>>(row, col, cursor, dinv, csr_src, csr_w, E, N, E4);
    k_pad<<<nb, 256, 0, stream>>>(cnt, offs, cursor, csr_src, csr_w, N);

    const int g64 = (N + 63) / 64;
    // layer 1: act1 = relu( (Â x) W1 + b1 )
    k_cvt_bf<<<(unsigned)(((size_t)N * 128 + 255) / 256), 256, 0, stream>>>(x, xb, (size_t)N * 128);
    k_aggb<128, false, false, USEW><<<(unsigned)(((size_t)N * 64 + 255) / 256), 256, 0, stream>>>(xb, xa, offs, csr_src, csr_w, dinv, nullptr, N, E4);
    k_gemm2<256, true, float><<<g64, 256, 0, stream>>>(xa, W1, act, b1, N, 128);
    // layer 2
    k_gemm2<128, false, unsigned short><<<g64, 256, 0, stream>>>(act, W2, H, nullptr, N, 256);
    k_aggb<128, true, true, USEW><<<(unsigned)(((size_t)N * 64 + 255) / 256), 256, 0, stream>>>(H, act, offs, csr_src, csr_w, dinv, b2, N, E4);
    // layer 3
    k_gemm2<64, false, unsigned short><<<g64, 256, 0, stream>>>(act, W3, H, nullptr, N, 128);
    k_aggb<64, true, true, USEW><<<(unsigned)(((size_t)N * 32 + 255) / 256), 256, 0, stream>>>(H, act, offs, csr_src, csr_w, dinv, b3, N, E4);
    // layer 4
    k_gemm32<<<(N + 31) / 32, 256, 0, stream>>>(act, W4, H, N);
    k_aggb<32, true, true, USEW><<<(unsigned)(((size_t)N * 16 + 255) / 256), 256, 0, stream>>>(H, act, offs, csr_src, csr_w, dinv, b4, N, E4);
    // fused heads
    float* outF = (float*)d_out;
    k_gemm_heads<<<(unsigned)(((size_t)N * 32 + 255) / 256), 256, 0, stream>>>(act, Wmu, Wls, H, N);
    k_agg_heads<USEW><<<(unsigned)(((size_t)N * 16 + 255) / 256), 256, 0, stream>>>(H, outF, offs, csr_src, csr_w, dinv, bmu, bls, N, E4);
}

extern "C" void kernel_launch(void* const* d_in, const int* in_sizes, int n_in,
                              void* d_out, int out_size, void* d_ws, size_t ws_size,
                              hipStream_t stream) {
    const int N = in_sizes[0] / 128;
    const int E = in_sizes[1] / 2;
    const int nb = (N + 255) / 256;
    const size_t E4 = (size_t)E + 4 * (size_t)N;

    size_t fixed = (size_t)N * 256 * 4 + (size_t)N * 256 * 2 + (size_t)N * 128 * 4
                 + (size_t)N * 4 * 5 + 4 + (size_t)nb * 8 + 64;
    size_t need_w = fixed + E4 * 8;
    if (ws_size >= need_w)
        run_pipeline<true>(d_in, d_out, d_ws, N, E, stream);
    else
        run_pipeline<false>(d_in, d_out, d_ws, N, E, stream);
}

// Round 11
// 442.143 us; speedup vs baseline: 2.4294x; 1.0963x over previous
//
#include <hip/hip_runtime.h>
#include <hip/hip_bf16.h>
#include <stdint.h>

__device__ inline int imin(int a, int b) { return a < b ? a : b; }
__device__ inline int imax(int a, int b) { return a > b ? a : b; }
__device__ inline float bf2f(unsigned short u) {
    return __uint_as_float(((unsigned int)u) << 16);
}
__device__ inline unsigned short f2bf(float v) {
    unsigned int u = __float_as_uint(v);
    unsigned int r = u + 0x7FFFu + ((u >> 16) & 1u);
    return (unsigned short)(r >> 16);
}
__device__ inline float4 ld4(const float* p) { return *(const float4*)p; }

typedef __attribute__((ext_vector_type(8))) short short8;   // 8 bf16 = 4 VGPRs
typedef __attribute__((ext_vector_type(4))) float floatx4;  // MFMA C/D

// ---------------- CSR build (padded-to-4 segments) ----------------

__global__ void k_zero_i32(int* __restrict__ p, int n) {
    int i = blockIdx.x * blockDim.x + threadIdx.x;
    if (i < n) p[i] = 0;
}

__global__ void k_count(const int* __restrict__ col, int* __restrict__ cnt, int E, int n) {
    int e = blockIdx.x * blockDim.x + threadIdx.x;
    if (e < E) {
        int c = imax(0, imin(col[e], n - 1));
        atomicAdd(&cnt[c], 1);
    }
}

__global__ __launch_bounds__(256) void k_scan1(const int* __restrict__ cnt,
                                               int* __restrict__ partial,
                                               int* __restrict__ bsum, int n) {
    __shared__ int tmp[256];
    int i = blockIdx.x * 256 + threadIdx.x;
    int v = (i < n) ? ((cnt[i] + 3) & ~3) : 0;
    tmp[threadIdx.x] = v;
    __syncthreads();
    #pragma unroll
    for (int s = 1; s < 256; s <<= 1) {
        int t = (threadIdx.x >= s) ? tmp[threadIdx.x - s] : 0;
        __syncthreads();
        tmp[threadIdx.x] += t;
        __syncthreads();
    }
    if (i < n) partial[i] = tmp[threadIdx.x] - v;
    if (threadIdx.x == 255) bsum[blockIdx.x] = tmp[255];
}

__global__ __launch_bounds__(256) void k_scan2(const int* __restrict__ bsum,
                                               int* __restrict__ bsumoff, int nb) {
    __shared__ int tmp[256];
    __shared__ int carry;
    if (threadIdx.x == 0) carry = 0;
    __syncthreads();
    for (int base = 0; base < nb; base += 256) {
        int i = base + threadIdx.x;
        int v = (i < nb) ? bsum[i] : 0;
        tmp[threadIdx.x] = v;
        __syncthreads();
        #pragma unroll
        for (int s = 1; s < 256; s <<= 1) {
            int t = (threadIdx.x >= s) ? tmp[threadIdx.x - s] : 0;
            __syncthreads();
            tmp[threadIdx.x] += t;
            __syncthreads();
        }
        if (i < nb) bsumoff[i] = carry + tmp[threadIdx.x] - v;
        __syncthreads();
        if (threadIdx.x == 0) carry += tmp[255];
        __syncthreads();
    }
}

__global__ __launch_bounds__(256) void k_scan3(const int* __restrict__ partial,
                                               const int* __restrict__ bsumoff,
                                               const int* __restrict__ cnt,
                                               int* __restrict__ offs, int* __restrict__ cursor,
                                               float* __restrict__ dinv, int n) {
    int i = blockIdx.x * 256 + threadIdx.x;
    if (i >= n) return;
    int v = partial[i] + bsumoff[blockIdx.x];
    offs[i] = v;
    cursor[i] = v;
    if (i == n - 1) offs[n] = v + ((cnt[i] + 3) & ~3);
    float d = (float)imax(cnt[i], 0) + 1.0f;
    dinv[i] = rsqrtf(d);
}

__global__ void k_fill(const int* __restrict__ row, const int* __restrict__ col,
                       int* __restrict__ cursor, const float* __restrict__ dinv,
                       int* __restrict__ csr_src, float* __restrict__ csr_w,
                       int E, int n, int cap) {
    int e = blockIdx.x * blockDim.x + threadIdx.x;
    if (e >= E) return;
    int c = imax(0, imin(col[e], n - 1));
    int r = imax(0, imin(row[e], n - 1));
    int pos = atomicAdd(&cursor[c], 1);
    pos = imax(0, imin(pos, cap - 1));
    csr_src[pos] = r;
    if (csr_w) csr_w[pos] = dinv[r];
}

__global__ void k_pad(const int* __restrict__ cnt, const int* __restrict__ offs,
                      const int* __restrict__ cursor,
                      int* __restrict__ csr_src, float* __restrict__ csr_w, int n) {
    int i = blockIdx.x * blockDim.x + threadIdx.x;
    if (i >= n) return;
    int end = offs[i] + ((cnt[i] + 3) & ~3);
    for (int p = cursor[i]; p < end; p++) {
        csr_src[p] = 0;
        if (csr_w) csr_w[p] = 0.f;
    }
}

// ---------------- casts ----------------

__global__ void k_cvt_bf(const float* __restrict__ in, unsigned short* __restrict__ out, size_t n) {
    size_t i = (size_t)blockIdx.x * 256 + threadIdx.x;
    if (i < n) out[i] = f2bf(in[i]);
}

// W [K][Nc] fp32 -> WT [Nc][K] bf16
__global__ void k_wcast(const float* __restrict__ W, unsigned short* __restrict__ WT,
                        int K, int Nc) {
    int idx = blockIdx.x * 256 + threadIdx.x;
    if (idx >= K * Nc) return;
    int k = idx / Nc, n = idx % Nc;
    WT[(size_t)n * K + k] = f2bf(W[idx]);
}

// ---------------- MFMA GEMM: H = act(fp32, cast bf16) @ W(bf16 WT), fp32 acc ----------------
// block: 256 rows x NT cols; 4 waves, wave w = rows w*64..w*64+63 (4 row-tiles of 16).
// per K-chunk(32): per-wave 4 A-frag reads + (NT/16) B-frag reads + 4*(NT/16) mfma.
// LDS rows stride 40 shorts (80 B) -> 2-way bank aliasing only.
// Verified layouts: A[m=lane&15][k=quad*8+j]; B[k][n=lane&15]; C/D row=quad*4+reg, col=lane&15.

template <int NT, int FOUT, bool EPI, typename OT>
__global__ __launch_bounds__(256) void k_gemm_mfma(const float* __restrict__ act,
                                                   const unsigned short* __restrict__ WT,
                                                   OT* __restrict__ H,
                                                   const float* __restrict__ bias,
                                                   int nrows, int Fin) {
    constexpr int CT = NT / 16;
    __shared__ __align__(16) unsigned short sA[256 * 40];
    __shared__ __align__(16) unsigned short sB[NT * 40];
    const int tid = threadIdx.x;
    const int w = tid >> 6;
    const int lane = tid & 63;
    const int quad = lane >> 4;
    const int l15 = lane & 15;
    const int row0 = blockIdx.x * 256;
    const int col0 = blockIdx.y * NT;

    floatx4 acc[4][CT] = {};

    for (int k0 = 0; k0 < Fin; k0 += 32) {
        __syncthreads();
        // stage A: thread tid stages row row0+tid, k0..k0+31 (fp32 -> bf16)
        {
            int grow = row0 + tid;
            __align__(16) unsigned short tmp[32];
            if (grow < nrows) {
                const float* ap = &act[(size_t)grow * Fin + k0];
                #pragma unroll
                for (int j = 0; j < 32; j += 4) {
                    float4 v = ld4(ap + j);
                    tmp[j] = f2bf(v.x); tmp[j + 1] = f2bf(v.y);
                    tmp[j + 2] = f2bf(v.z); tmp[j + 3] = f2bf(v.w);
                }
            } else {
                #pragma unroll
                for (int j = 0; j < 32; j++) tmp[j] = 0;
            }
            uint4* dst = (uint4*)&sA[tid * 40];
            const uint4* sv = (const uint4*)tmp;
            #pragma unroll
            for (int j = 0; j < 4; j++) dst[j] = sv[j];
        }
        // stage B: thread t < NT stages col col0+t from WT[col][k0..k0+31]
        if (tid < NT) {
            const uint4* wp = (const uint4*)&WT[(size_t)(col0 + tid) * Fin + k0];
            uint4* dst = (uint4*)&sB[tid * 40];
            #pragma unroll
            for (int j = 0; j < 4; j++) dst[j] = wp[j];
        }
        __syncthreads();

        short8 bfr[CT];
        #pragma unroll
        for (int ct = 0; ct < CT; ct++)
            bfr[ct] = *(const short8*)&sB[(ct * 16 + l15) * 40 + quad * 8];
        #pragma unroll
        for (int rt = 0; rt < 4; rt++) {
            short8 afr = *(const short8*)&sA[(w * 64 + rt * 16 + l15) * 40 + quad * 8];
            #pragma unroll
            for (int ct = 0; ct < CT; ct++)
                acc[rt][ct] = __builtin_amdgcn_mfma_f32_16x16x32_bf16(afr, bfr[ct], acc[rt][ct], 0, 0, 0);
        }
    }

    // epilogue: C/D row = quad*4 + reg, col = lane&15
    #pragma unroll
    for (int rt = 0; rt < 4; rt++) {
        #pragma unroll
        for (int ct = 0; ct < CT; ct++) {
            int gcol = col0 + ct * 16 + l15;
            #pragma unroll
            for (int r = 0; r < 4; r++) {
                int grow = row0 + w * 64 + rt * 16 + quad * 4 + r;
                if (grow < nrows) {
                    float v = acc[rt][ct][r];
                    if (EPI) v = fmaxf(v + bias[gcol], 0.f);
                    OT* hp = &H[(size_t)grow * FOUT + gcol];
                    if (sizeof(OT) == 4) *(float*)hp = v;
                    else *(unsigned short*)hp = f2bf(v);
                }
            }
        }
    }
}

// ---------------- small GEMMs (unchanged, fp32 act in, bf16 out) ----------------

__global__ __launch_bounds__(256) void k_gemm32(const float* __restrict__ act,
                                                const float* __restrict__ W,
                                                unsigned short* __restrict__ H,
                                                int nrows) {
    __shared__ __align__(16) float sA[32 * 68];
    __shared__ __align__(16) float sW[16 * 32];
    const int tid = threadIdx.x;
    const int row0 = blockIdx.x * 32;
    const int Fin = 64, strA = 68;

    for (int i = tid; i < 32 * Fin; i += 256) {
        int r = i >> 6;
        int k = i & 63;
        float v = 0.f;
        if (row0 + r < nrows) v = act[(size_t)row0 * Fin + i];
        sA[r * strA + k] = v;
    }

    const int rl = tid >> 3;
    const int cg = tid & 7;
    float a0 = 0.f, a1 = 0.f, a2 = 0.f, a3 = 0.f;

    for (int k0 = 0; k0 < Fin; k0 += 16) {
        __syncthreads();
        const float* wsrc = W + (size_t)k0 * 32;
        for (int i = tid; i < 16 * 32; i += 256) sW[i] = wsrc[i];
        __syncthreads();
        #pragma unroll 4
        for (int kk = 0; kk < 16; kk++) {
            float a = sA[rl * strA + k0 + kk];
            float4 wv = *(const float4*)&sW[kk * 32 + cg * 4];
            a0 = fmaf(a, wv.x, a0);
            a1 = fmaf(a, wv.y, a1);
            a2 = fmaf(a, wv.z, a2);
            a3 = fmaf(a, wv.w, a3);
        }
    }

    const int rowi = row0 + rl;
    if (rowi < nrows) {
        unsigned short* hp = &H[(size_t)rowi * 32 + cg * 4];
        hp[0] = f2bf(a0); hp[1] = f2bf(a1); hp[2] = f2bf(a2); hp[3] = f2bf(a3);
    }
}

__global__ void k_gemm_heads(const float* __restrict__ act,
                             const float* __restrict__ Wmu, const float* __restrict__ Wls,
                             unsigned short* __restrict__ H, int nrows) {
    int idx = blockIdx.x * blockDim.x + threadIdx.x;
    if (idx >= nrows * 32) return;
    int r = idx >> 5;
    int c = idx & 31;
    const float* Wp = (c < 16) ? Wmu : Wls;
    int cc = c & 15;
    float acc = 0.f;
    #pragma unroll 8
    for (int k = 0; k < 32; k++)
        acc = fmaf(act[(size_t)r * 32 + k], Wp[k * 16 + cc], acc);
    H[idx] = f2bf(acc);
}

// ---- aggregation over bf16 H, 4x-unrolled padded CSR (unchanged) ----

template <int F, bool RELU, bool HASBIAS, bool USEW>
__global__ __launch_bounds__(256) void k_aggb(const unsigned short* __restrict__ Hb,
                                              float* __restrict__ out,
                                              const int* __restrict__ offs, const int* __restrict__ src,
                                              const float* __restrict__ w,
                                              const float* __restrict__ dinv,
                                              const float* __restrict__ bias,
                                              int nnodes, int Ecap) {
    constexpr int TPN = (F >= 128) ? 64 : F / 2;
    int t = blockIdx.x * 256 + threadIdx.x;
    int node = t / TPN;
    int ln = t % TPN;
    if (node >= nnodes) return;
    int f0 = 2 * ln;

    float di = dinv[node];
    ushort2 sv = *(const ushort2*)&Hb[(size_t)node * F + f0];
    float acc0 = di * bf2f(sv.x);
    float acc1 = di * bf2f(sv.y);

    int s0 = offs[node];
    int s1 = offs[node + 1];
    s0 = imax(0, imin(s0, Ecap));
    s1 = imax(s0, imin(s1, Ecap));
    for (int e = s0; e < s1; e += 4) {
        const int4 sr4 = *(const int4*)(src + e);
        float w0, w1, w2, w3;
        if (USEW) {
            const float4 w4 = *(const float4*)(w + e);
            w0 = w4.x; w1 = w4.y; w2 = w4.z; w3 = w4.w;
        } else {
            w0 = dinv[sr4.x]; w1 = dinv[sr4.y]; w2 = dinv[sr4.z]; w3 = dinv[sr4.w];
        }
        ushort2 h0 = *(const ushort2*)&Hb[(size_t)sr4.x * F + f0];
        ushort2 h1 = *(const ushort2*)&Hb[(size_t)sr4.y * F + f0];
        ushort2 h2 = *(const ushort2*)&Hb[(size_t)sr4.z * F + f0];
        ushort2 h3 = *(const ushort2*)&Hb[(size_t)sr4.w * F + f0];
        acc0 = fmaf(w0, bf2f(h0.x), acc0);
        acc1 = fmaf(w0, bf2f(h0.y), acc1);
        acc0 = fmaf(w1, bf2f(h1.x), acc0);
        acc1 = fmaf(w1, bf2f(h1.y), acc1);
        acc0 = fmaf(w2, bf2f(h2.x), acc0);
        acc1 = fmaf(w2, bf2f(h2.y), acc1);
        acc0 = fmaf(w3, bf2f(h3.x), acc0);
        acc1 = fmaf(w3, bf2f(h3.y), acc1);
    }
    float v0 = di * acc0;
    float v1 = di * acc1;
    if (HASBIAS) { v0 += bias[f0]; v1 += bias[f0 + 1]; }
    if (RELU) { v0 = fmaxf(v0, 0.f); v1 = fmaxf(v1, 0.f); }
    *(float2*)&out[(size_t)node * F + f0] = make_float2(v0, v1);
}

template <bool USEW>
__global__ __launch_bounds__(256) void k_agg_heads(const unsigned short* __restrict__ Hb,
                                                   float* __restrict__ out,
                                                   const int* __restrict__ offs, const int* __restrict__ src,
                                                   const float* __restrict__ w,
                                                   const float* __restrict__ dinv,
                                                   const float* __restrict__ bmu, const float* __restrict__ bls,
                                                   int nnodes, int Ecap) {
    constexpr int F = 32, TPN = 16;
    int t = blockIdx.x * 256 + threadIdx.x;
    int node = t / TPN;
    int ln = t % TPN;
    if (node >= nnodes) return;
    int f0 = 2 * ln;

    float di = dinv[node];
    ushort2 sv = *(const ushort2*)&Hb[(size_t)node * F + f0];
    float acc0 = di * bf2f(sv.x);
    float acc1 = di * bf2f(sv.y);

    int s0 = offs[node];
    int s1 = offs[node + 1];
    s0 = imax(0, imin(s0, Ecap));
    s1 = imax(s0, imin(s1, Ecap));
    for (int e = s0; e < s1; e += 4) {
        const int4 sr4 = *(const int4*)(src + e);
        float w0, w1, w2, w3;
        if (USEW) {
            const float4 w4 = *(const float4*)(w + e);
            w0 = w4.x; w1 = w4.y; w2 = w4.z; w3 = w4.w;
        } else {
            w0 = dinv[sr4.x]; w1 = dinv[sr4.y]; w2 = dinv[sr4.z]; w3 = dinv[sr4.w];
        }
        ushort2 h0 = *(const ushort2*)&Hb[(size_t)sr4.x * F + f0];
        ushort2 h1 = *(const ushort2*)&Hb[(size_t)sr4.y * F + f0];
        ushort2 h2 = *(const ushort2*)&Hb[(size_t)sr4.z * F + f0];
        ushort2 h3 = *(const ushort2*)&Hb[(size_t)sr4.w * F + f0];
        acc0 = fmaf(w0, bf2f(h0.x), acc0);
        acc1 = fmaf(w0, bf2f(h0.y), acc1);
        acc0 = fmaf(w1, bf2f(h1.x), acc0);
        acc1 = fmaf(w1, bf2f(h1.y), acc1);
        acc0 = fmaf(w2, bf2f(h2.x), acc0);
        acc1 = fmaf(w2, bf2f(h2.y), acc1);
        acc0 = fmaf(w3, bf2f(h3.x), acc0);
        acc1 = fmaf(w3, bf2f(h3.y), acc1);
    }
    const float* bp = (f0 < 16) ? bmu : bls;
    int fb = f0 & 15;
    float v0 = fmaf(di, acc0, bp[fb]);
    float v1 = fmaf(di, acc1, bp[fb + 1]);
    float* op = (f0 < 16) ? (out + (size_t)node * 16 + fb)
                          : (out + (size_t)nnodes * 16 + (size_t)node * 16 + fb);
    *(float2*)op = make_float2(v0, v1);
}

// ---------------- pipeline ----------------

template <bool USEW>
static void run_pipeline(void* const* d_in, void* d_out, void* d_ws,
                         int N, int E, hipStream_t stream) {
    const float* x  = (const float*)d_in[0];
    const int* ei   = (const int*)d_in[1];
    const float* W1 = (const float*)d_in[2];
    const float* b1 = (const float*)d_in[3];
    const float* W2 = (const float*)d_in[4];
    const float* b2 = (const float*)d_in[5];
    const float* W3 = (const float*)d_in[6];
    const float* b3 = (const float*)d_in[7];
    const float* W4 = (const float*)d_in[8];
    const float* b4 = (const float*)d_in[9];
    const float* Wmu = (const float*)d_in[10];
    const float* bmu = (const float*)d_in[11];
    const float* Wls = (const float*)d_in[12];
    const float* bls = (const float*)d_in[13];
    const int* row = ei;        // edge_index[0] = source
    const int* col = ei + E;    // edge_index[1] = target
    const int nb = (N + 255) / 256;
    const int E4 = E + 4 * N;

    auto align16 = [](char* p) {
        return (char*)(((uintptr_t)p + 15) & ~(uintptr_t)15);
    };
    char* p = (char*)d_ws;
    float* act = (float*)p;                      p += (size_t)N * 256 * 4;
    unsigned short* H = (unsigned short*)p;      p += (size_t)N * 256 * 2;
    unsigned short* xb = H;                      // alias (dead before H first write)
    float* xa = (float*)p;                       p += (size_t)N * 128 * 4;
    float* dinv = (float*)p;                     p += (size_t)N * 4;
    int* cnt = (int*)p;                          p += (size_t)N * 4;
    int* offs = (int*)p;                         p += (size_t)(N + 1) * 4;
    int* cursor = (int*)p;                       p += (size_t)N * 4;
    int* partial = (int*)p;                      p += (size_t)N * 4;
    int* bsum = (int*)p;                         p += (size_t)nb * 4;
    int* bsumoff = (int*)p;                      p += (size_t)nb * 4;
    p = align16(p);
    unsigned short* W1T = (unsigned short*)p;    p += 256 * 128 * 2;   // [FOUT=256][Fin=128]
    unsigned short* W2T = (unsigned short*)p;    p += 128 * 256 * 2;   // [128][256]
    unsigned short* W3T = (unsigned short*)p;    p += 64 * 128 * 2;    // [64][128]
    p = align16(p);
    int* csr_src = (int*)p;                      p += (size_t)E4 * 4;
    p = align16(p);
    float* csr_w = USEW ? (float*)p : nullptr;

    // CSR + norms
    k_zero_i32<<<nb, 256, 0, stream>>>(cnt, N);
    k_count<<<(E + 255) / 256, 256, 0, stream>>>(col, cnt, E, N);
    k_scan1<<<nb, 256, 0, stream>>>(cnt, partial, bsum, N);
    k_scan2<<<1, 256, 0, stream>>>(bsum, bsumoff, nb);
    k_scan3<<<nb, 256, 0, stream>>>(partial, bsumoff, cnt, offs, cursor, dinv, N);
    k_fill<<<(E + 255) / 256, 256, 0, stream>>>(row, col, cursor, dinv, csr_src, csr_w, E, N, E4);
    k_pad<<<nb, 256, 0, stream>>>(cnt, offs, cursor, csr_src, csr_w, N);

    // weight casts (bf16, transposed)
    k_wcast<<<(128 * 256 + 255) / 256, 256, 0, stream>>>(W1, W1T, 128, 256);
    k_wcast<<<(256 * 128 + 255) / 256, 256, 0, stream>>>(W2, W2T, 256, 128);
    k_wcast<<<(128 * 64 + 255) / 256, 256, 0, stream>>>(W3, W3T, 128, 64);

    const int gx = (N + 255) / 256;
    // layer 1: act1 = relu( (Â x) W1 + b1 )
    k_cvt_bf<<<(unsigned)(((size_t)N * 128 + 255) / 256), 256, 0, stream>>>(x, xb, (size_t)N * 128);
    k_aggb<128, false, false, USEW><<<(unsigned)(((size_t)N * 64 + 255) / 256), 256, 0, stream>>>(xb, xa, offs, csr_src, csr_w, dinv, nullptr, N, E4);
    k_gemm_mfma<128, 256, true, float><<<dim3(gx, 2), 256, 0, stream>>>(xa, W1T, act, b1, N, 128);
    // layer 2
    k_gemm_mfma<128, 128, false, unsigned short><<<dim3(gx, 1), 256, 0, stream>>>(act, W2T, H, nullptr, N, 256);
    k_aggb<128, true, true, USEW><<<(unsigned)(((size_t)N * 64 + 255) / 256), 256, 0, stream>>>(H, act, offs, csr_src, csr_w, dinv, b2, N, E4);
    // layer 3
    k_gemm_mfma<64, 64, false, unsigned short><<<dim3(gx, 1), 256, 0, stream>>>(act, W3T, H, nullptr, N, 128);
    k_aggb<64, true, true, USEW><<<(unsigned)(((size_t)N * 32 + 255) / 256), 256, 0, stream>>>(H, act, offs, csr_src, csr_w, dinv, b3, N, E4);
    // layer 4
    k_gemm32<<<(N + 31) / 32, 256, 0, stream>>>(act, W4, H, N);
    k_aggb<32, true, true, USEW><<<(unsigned)(((size_t)N * 16 + 255) / 256), 256, 0, stream>>>(H, act, offs, csr_src, csr_w, dinv, b4, N, E4);
    // fused heads
    float* outF = (float*)d_out;
    k_gemm_heads<<<(unsigned)(((size_t)N * 32 + 255) / 256), 256, 0, stream>>>(act, Wmu, Wls, H, N);
    k_agg_heads<USEW><<<(unsigned)(((size_t)N * 16 + 255) / 256), 256, 0, stream>>>(H, outF, offs, csr_src, csr_w, dinv, bmu, bls, N, E4);
}

extern "C" void kernel_launch(void* const* d_in, const int* in_sizes, int n_in,
                              void* d_out, int out_size, void* d_ws, size_t ws_size,
                              hipStream_t stream) {
    const int N = in_sizes[0] / 128;
    const int E = in_sizes[1] / 2;
    const int nb = (N + 255) / 256;
    const size_t E4 = (size_t)E + 4 * (size_t)N;

    size_t fixed = (size_t)N * 256 * 4 + (size_t)N * 256 * 2 + (size_t)N * 128 * 4
                 + (size_t)N * 4 * 5 + 4 + (size_t)nb * 8
                 + (256 * 128 + 128 * 256 + 64 * 128) * 2 + 96;
    size_t need_w = fixed + E4 * 8;
    if (ws_size >= need_w)
        run_pipeline<true>(d_in, d_out, d_ws, N, E, stream);
    else
        run_pipeline<false>(d_in, d_out, d_ws, N, E, stream);
}

// Round 12
// 397.539 us; speedup vs baseline: 2.7020x; 1.1122x over previous
//
#include <hip/hip_runtime.h>
#include <hip/hip_bf16.h>
#include <stdint.h>

__device__ inline int imin(int a, int b) { return a < b ? a : b; }
__device__ inline int imax(int a, int b) { return a > b ? a : b; }
__device__ inline float bf2f(unsigned short u) {
    return __uint_as_float(((unsigned int)u) << 16);
}
__device__ inline unsigned short f2bf(float v) {
    unsigned int u = __float_as_uint(v);
    unsigned int r = u + 0x7FFFu + ((u >> 16) & 1u);
    return (unsigned short)(r >> 16);
}
__device__ inline float4 ld4(const float* p) { return *(const float4*)p; }

typedef __attribute__((ext_vector_type(8))) short short8;   // 8 bf16 = 4 VGPRs
typedef __attribute__((ext_vector_type(4))) float floatx4;  // MFMA C/D

// ---------------- CSR build (padded-to-4 segments) ----------------

__global__ void k_zero_i32(int* __restrict__ p, int n) {
    int i = blockIdx.x * blockDim.x + threadIdx.x;
    if (i < n) p[i] = 0;
}

__global__ void k_count(const int* __restrict__ col, int* __restrict__ cnt, int E, int n) {
    int e = blockIdx.x * blockDim.x + threadIdx.x;
    if (e < E) {
        int c = imax(0, imin(col[e], n - 1));
        atomicAdd(&cnt[c], 1);
    }
}

__global__ __launch_bounds__(256) void k_scan1(const int* __restrict__ cnt,
                                               int* __restrict__ partial,
                                               int* __restrict__ bsum, int n) {
    __shared__ int tmp[256];
    int i = blockIdx.x * 256 + threadIdx.x;
    int v = (i < n) ? ((cnt[i] + 3) & ~3) : 0;
    tmp[threadIdx.x] = v;
    __syncthreads();
    #pragma unroll
    for (int s = 1; s < 256; s <<= 1) {
        int t = (threadIdx.x >= s) ? tmp[threadIdx.x - s] : 0;
        __syncthreads();
        tmp[threadIdx.x] += t;
        __syncthreads();
    }
    if (i < n) partial[i] = tmp[threadIdx.x] - v;
    if (threadIdx.x == 255) bsum[blockIdx.x] = tmp[255];
}

__global__ __launch_bounds__(256) void k_scan2(const int* __restrict__ bsum,
                                               int* __restrict__ bsumoff, int nb) {
    __shared__ int tmp[256];
    __shared__ int carry;
    if (threadIdx.x == 0) carry = 0;
    __syncthreads();
    for (int base = 0; base < nb; base += 256) {
        int i = base + threadIdx.x;
        int v = (i < nb) ? bsum[i] : 0;
        tmp[threadIdx.x] = v;
        __syncthreads();
        #pragma unroll
        for (int s = 1; s < 256; s <<= 1) {
            int t = (threadIdx.x >= s) ? tmp[threadIdx.x - s] : 0;
            __syncthreads();
            tmp[threadIdx.x] += t;
            __syncthreads();
        }
        if (i < nb) bsumoff[i] = carry + tmp[threadIdx.x] - v;
        __syncthreads();
        if (threadIdx.x == 0) carry += tmp[255];
        __syncthreads();
    }
}

__global__ __launch_bounds__(256) void k_scan3(const int* __restrict__ partial,
                                               const int* __restrict__ bsumoff,
                                               const int* __restrict__ cnt,
                                               int* __restrict__ offs, int* __restrict__ cursor,
                                               float* __restrict__ dinv, int n) {
    int i = blockIdx.x * 256 + threadIdx.x;
    if (i >= n) return;
    int v = partial[i] + bsumoff[blockIdx.x];
    offs[i] = v;
    cursor[i] = v;
    if (i == n - 1) offs[n] = v + ((cnt[i] + 3) & ~3);
    float d = (float)imax(cnt[i], 0) + 1.0f;
    dinv[i] = rsqrtf(d);
}

__global__ void k_fill(const int* __restrict__ row, const int* __restrict__ col,
                       int* __restrict__ cursor, const float* __restrict__ dinv,
                       int* __restrict__ csr_src, float* __restrict__ csr_w,
                       int E, int n, int cap) {
    int e = blockIdx.x * blockDim.x + threadIdx.x;
    if (e >= E) return;
    int c = imax(0, imin(col[e], n - 1));
    int r = imax(0, imin(row[e], n - 1));
    int pos = atomicAdd(&cursor[c], 1);
    pos = imax(0, imin(pos, cap - 1));
    csr_src[pos] = r;
    if (csr_w) csr_w[pos] = dinv[r];
}

__global__ void k_pad(const int* __restrict__ cnt, const int* __restrict__ offs,
                      const int* __restrict__ cursor,
                      int* __restrict__ csr_src, float* __restrict__ csr_w, int n) {
    int i = blockIdx.x * blockDim.x + threadIdx.x;
    if (i >= n) return;
    int end = offs[i] + ((cnt[i] + 3) & ~3);
    for (int p = cursor[i]; p < end; p++) {
        csr_src[p] = 0;
        if (csr_w) csr_w[p] = 0.f;
    }
}

// ---------------- casts ----------------

__global__ void k_cvt_bf(const float* __restrict__ in, unsigned short* __restrict__ out, size_t n) {
    size_t i = (size_t)blockIdx.x * 256 + threadIdx.x;
    if (i < n) out[i] = f2bf(in[i]);
}

// W [K][Nc] fp32 -> WT [Nc][K] bf16
__global__ void k_wcast(const float* __restrict__ W, unsigned short* __restrict__ WT,
                        int K, int Nc) {
    int idx = blockIdx.x * 256 + threadIdx.x;
    if (idx >= K * Nc) return;
    int k = idx / Nc, n = idx % Nc;
    WT[(size_t)n * K + k] = f2bf(W[idx]);
}

// ---------------- MFMA GEMM: H = act(bf16) @ W(bf16 WT), fp32 acc, bf16 out ----------------
// block: 128 rows x NT cols; wave w = rows w*32..w*32+31 (2 row-tiles of 16).
// LDS rows stride 40 shorts (80 B) -> 2-way bank aliasing only (free).
// Verified layouts: A[m=lane&15][k=quad*8+j]; B[k][n=lane&15]; C/D row=quad*4+reg, col=lane&15.

template <int NT, int FOUT, bool EPI>
__global__ __launch_bounds__(256) void k_gemm_mfma(const unsigned short* __restrict__ act,
                                                   const unsigned short* __restrict__ WT,
                                                   unsigned short* __restrict__ H,
                                                   const float* __restrict__ bias,
                                                   int nrows, int Fin) {
    constexpr int CT = NT / 16;
    __shared__ __align__(16) unsigned short sA[128 * 40];
    __shared__ __align__(16) unsigned short sB[NT * 40];
    const int tid = threadIdx.x;
    const int w = tid >> 6;
    const int lane = tid & 63;
    const int quad = lane >> 4;
    const int l15 = lane & 15;
    const int row0 = blockIdx.x * 128;
    const int col0 = blockIdx.y * NT;

    floatx4 acc[2][CT] = {};

    const int sr = tid >> 1;            // staging row/col index (0..127)
    const int sp = (tid & 1) * 16;      // staging k offset (16 shorts = 32 B)

    for (int k0 = 0; k0 < Fin; k0 += 32) {
        __syncthreads();
        // stage A: 128 rows x 32 k bf16; 2 threads/row, 16 shorts each
        {
            int grow = row0 + sr;
            uint4 v0 = make_uint4(0, 0, 0, 0), v1 = make_uint4(0, 0, 0, 0);
            if (grow < nrows) {
                const uint4* ap = (const uint4*)&act[(size_t)grow * Fin + k0 + sp];
                v0 = ap[0]; v1 = ap[1];
            }
            uint4* dst = (uint4*)&sA[sr * 40 + sp];
            dst[0] = v0; dst[1] = v1;
        }
        // stage B: NT cols x 32 k
        if (NT == 128 || tid < 128) {
            const uint4* wp = (const uint4*)&WT[(size_t)(col0 + sr) * Fin + k0 + sp];
            uint4* dst = (uint4*)&sB[sr * 40 + sp];
            dst[0] = wp[0]; dst[1] = wp[1];
        }
        __syncthreads();

        short8 bfr[CT];
        #pragma unroll
        for (int ct = 0; ct < CT; ct++)
            bfr[ct] = *(const short8*)&sB[(ct * 16 + l15) * 40 + quad * 8];
        #pragma unroll
        for (int rt = 0; rt < 2; rt++) {
            short8 afr = *(const short8*)&sA[(w * 32 + rt * 16 + l15) * 40 + quad * 8];
            #pragma unroll
            for (int ct = 0; ct < CT; ct++)
                acc[rt][ct] = __builtin_amdgcn_mfma_f32_16x16x32_bf16(afr, bfr[ct], acc[rt][ct], 0, 0, 0);
        }
    }

    // epilogue: C/D row = quad*4 + reg, col = lane&15; bf16 store
    #pragma unroll
    for (int rt = 0; rt < 2; rt++) {
        #pragma unroll
        for (int ct = 0; ct < CT; ct++) {
            int gcol = col0 + ct * 16 + l15;
            #pragma unroll
            for (int r = 0; r < 4; r++) {
                int grow = row0 + w * 32 + rt * 16 + quad * 4 + r;
                if (grow < nrows) {
                    float v = acc[rt][ct][r];
                    if (EPI) v = fmaxf(v + bias[gcol], 0.f);
                    H[(size_t)grow * FOUT + gcol] = f2bf(v);
                }
            }
        }
    }
}

// ---------------- small GEMMs (bf16 act in, bf16 out) ----------------

__global__ __launch_bounds__(256) void k_gemm32(const unsigned short* __restrict__ act,
                                                const float* __restrict__ W,
                                                unsigned short* __restrict__ H,
                                                int nrows) {
    __shared__ __align__(16) float sA[32 * 68];
    __shared__ __align__(16) float sW[16 * 32];
    const int tid = threadIdx.x;
    const int row0 = blockIdx.x * 32;
    const int Fin = 64, strA = 68;

    for (int i = tid; i < 32 * Fin; i += 256) {
        int r = i >> 6;
        int k = i & 63;
        float v = 0.f;
        if (row0 + r < nrows) v = bf2f(act[(size_t)row0 * Fin + i]);
        sA[r * strA + k] = v;
    }

    const int rl = tid >> 3;
    const int cg = tid & 7;
    float a0 = 0.f, a1 = 0.f, a2 = 0.f, a3 = 0.f;

    for (int k0 = 0; k0 < Fin; k0 += 16) {
        __syncthreads();
        const float* wsrc = W + (size_t)k0 * 32;
        for (int i = tid; i < 16 * 32; i += 256) sW[i] = wsrc[i];
        __syncthreads();
        #pragma unroll 4
        for (int kk = 0; kk < 16; kk++) {
            float a = sA[rl * strA + k0 + kk];
            float4 wv = *(const float4*)&sW[kk * 32 + cg * 4];
            a0 = fmaf(a, wv.x, a0);
            a1 = fmaf(a, wv.y, a1);
            a2 = fmaf(a, wv.z, a2);
            a3 = fmaf(a, wv.w, a3);
        }
    }

    const int rowi = row0 + rl;
    if (rowi < nrows) {
        unsigned short* hp = &H[(size_t)rowi * 32 + cg * 4];
        hp[0] = f2bf(a0); hp[1] = f2bf(a1); hp[2] = f2bf(a2); hp[3] = f2bf(a3);
    }
}

__global__ void k_gemm_heads(const unsigned short* __restrict__ act,
                             const float* __restrict__ Wmu, const float* __restrict__ Wls,
                             unsigned short* __restrict__ H, int nrows) {
    int idx = blockIdx.x * blockDim.x + threadIdx.x;
    if (idx >= nrows * 32) return;
    int r = idx >> 5;
    int c = idx & 31;
    const float* Wp = (c < 16) ? Wmu : Wls;
    int cc = c & 15;
    float acc = 0.f;
    #pragma unroll 8
    for (int k = 0; k < 32; k++)
        acc = fmaf(bf2f(act[(size_t)r * 32 + k]), Wp[k * 16 + cc], acc);
    H[idx] = f2bf(acc);
}

// ---- aggregation over bf16 H, 4x-unrolled padded CSR; bf16 out ----

template <int F, bool RELU, bool HASBIAS, bool USEW>
__global__ __launch_bounds__(256) void k_aggb(const unsigned short* __restrict__ Hb,
                                              unsigned short* __restrict__ out,
                                              const int* __restrict__ offs, const int* __restrict__ src,
                                              const float* __restrict__ w,
                                              const float* __restrict__ dinv,
                                              const float* __restrict__ bias,
                                              int nnodes, int Ecap) {
    constexpr int TPN = (F >= 128) ? 64 : F / 2;
    int t = blockIdx.x * 256 + threadIdx.x;
    int node = t / TPN;
    int ln = t % TPN;
    if (node >= nnodes) return;
    int f0 = 2 * ln;

    float di = dinv[node];
    ushort2 sv = *(const ushort2*)&Hb[(size_t)node * F + f0];
    float acc0 = di * bf2f(sv.x);
    float acc1 = di * bf2f(sv.y);

    int s0 = offs[node];
    int s1 = offs[node + 1];
    s0 = imax(0, imin(s0, Ecap));
    s1 = imax(s0, imin(s1, Ecap));
    for (int e = s0; e < s1; e += 4) {
        const int4 sr4 = *(const int4*)(src + e);
        float w0, w1, w2, w3;
        if (USEW) {
            const float4 w4 = *(const float4*)(w + e);
            w0 = w4.x; w1 = w4.y; w2 = w4.z; w3 = w4.w;
        } else {
            w0 = dinv[sr4.x]; w1 = dinv[sr4.y]; w2 = dinv[sr4.z]; w3 = dinv[sr4.w];
        }
        ushort2 h0 = *(const ushort2*)&Hb[(size_t)sr4.x * F + f0];
        ushort2 h1 = *(const ushort2*)&Hb[(size_t)sr4.y * F + f0];
        ushort2 h2 = *(const ushort2*)&Hb[(size_t)sr4.z * F + f0];
        ushort2 h3 = *(const ushort2*)&Hb[(size_t)sr4.w * F + f0];
        acc0 = fmaf(w0, bf2f(h0.x), acc0);
        acc1 = fmaf(w0, bf2f(h0.y), acc1);
        acc0 = fmaf(w1, bf2f(h1.x), acc0);
        acc1 = fmaf(w1, bf2f(h1.y), acc1);
        acc0 = fmaf(w2, bf2f(h2.x), acc0);
        acc1 = fmaf(w2, bf2f(h2.y), acc1);
        acc0 = fmaf(w3, bf2f(h3.x), acc0);
        acc1 = fmaf(w3, bf2f(h3.y), acc1);
    }
    float v0 = di * acc0;
    float v1 = di * acc1;
    if (HASBIAS) { v0 += bias[f0]; v1 += bias[f0 + 1]; }
    if (RELU) { v0 = fmaxf(v0, 0.f); v1 = fmaxf(v1, 0.f); }
    ushort2 o; o.x = f2bf(v0); o.y = f2bf(v1);
    *(ushort2*)&out[(size_t)node * F + f0] = o;
}

// fused heads aggregation: F=32 (mu 0..15, logstd 16..31), fp32 split output to d_out
template <bool USEW>
__global__ __launch_bounds__(256) void k_agg_heads(const unsigned short* __restrict__ Hb,
                                                   float* __restrict__ out,
                                                   const int* __restrict__ offs, const int* __restrict__ src,
                                                   const float* __restrict__ w,
                                                   const float* __restrict__ dinv,
                                                   const float* __restrict__ bmu, const float* __restrict__ bls,
                                                   int nnodes, int Ecap) {
    constexpr int F = 32, TPN = 16;
    int t = blockIdx.x * 256 + threadIdx.x;
    int node = t / TPN;
    int ln = t % TPN;
    if (node >= nnodes) return;
    int f0 = 2 * ln;

    float di = dinv[node];
    ushort2 sv = *(const ushort2*)&Hb[(size_t)node * F + f0];
    float acc0 = di * bf2f(sv.x);
    float acc1 = di * bf2f(sv.y);

    int s0 = offs[node];
    int s1 = offs[node + 1];
    s0 = imax(0, imin(s0, Ecap));
    s1 = imax(s0, imin(s1, Ecap));
    for (int e = s0; e < s1; e += 4) {
        const int4 sr4 = *(const int4*)(src + e);
        float w0, w1, w2, w3;
        if (USEW) {
            const float4 w4 = *(const float4*)(w + e);
            w0 = w4.x; w1 = w4.y; w2 = w4.z; w3 = w4.w;
        } else {
            w0 = dinv[sr4.x]; w1 = dinv[sr4.y]; w2 = dinv[sr4.z]; w3 = dinv[sr4.w];
        }
        ushort2 h0 = *(const ushort2*)&Hb[(size_t)sr4.x * F + f0];
        ushort2 h1 = *(const ushort2*)&Hb[(size_t)sr4.y * F + f0];
        ushort2 h2 = *(const ushort2*)&Hb[(size_t)sr4.z * F + f0];
        ushort2 h3 = *(const ushort2*)&Hb[(size_t)sr4.w * F + f0];
        acc0 = fmaf(w0, bf2f(h0.x), acc0);
        acc1 = fmaf(w0, bf2f(h0.y), acc1);
        acc0 = fmaf(w1, bf2f(h1.x), acc0);
        acc1 = fmaf(w1, bf2f(h1.y), acc1);
        acc0 = fmaf(w2, bf2f(h2.x), acc0);
        acc1 = fmaf(w2, bf2f(h2.y), acc1);
        acc0 = fmaf(w3, bf2f(h3.x), acc0);
        acc1 = fmaf(w3, bf2f(h3.y), acc1);
    }
    const float* bp = (f0 < 16) ? bmu : bls;
    int fb = f0 & 15;
    float v0 = fmaf(di, acc0, bp[fb]);
    float v1 = fmaf(di, acc1, bp[fb + 1]);
    float* op = (f0 < 16) ? (out + (size_t)node * 16 + fb)
                          : (out + (size_t)nnodes * 16 + (size_t)node * 16 + fb);
    *(float2*)op = make_float2(v0, v1);
}

// ---------------- pipeline ----------------

template <bool USEW>
static void run_pipeline(void* const* d_in, void* d_out, void* d_ws,
                         int N, int E, hipStream_t stream) {
    const float* x  = (const float*)d_in[0];
    const int* ei   = (const int*)d_in[1];
    const float* W1 = (const float*)d_in[2];
    const float* b1 = (const float*)d_in[3];
    const float* W2 = (const float*)d_in[4];
    const float* b2 = (const float*)d_in[5];
    const float* W3 = (const float*)d_in[6];
    const float* b3 = (const float*)d_in[7];
    const float* W4 = (const float*)d_in[8];
    const float* b4 = (const float*)d_in[9];
    const float* Wmu = (const float*)d_in[10];
    const float* bmu = (const float*)d_in[11];
    const float* Wls = (const float*)d_in[12];
    const float* bls = (const float*)d_in[13];
    const int* row = ei;        // edge_index[0] = source
    const int* col = ei + E;    // edge_index[1] = target
    const int nb = (N + 255) / 256;
    const int E4 = E + 4 * N;

    auto align16 = [](char* p) {
        return (char*)(((uintptr_t)p + 15) & ~(uintptr_t)15);
    };
    char* p = (char*)d_ws;
    unsigned short* act = (unsigned short*)p;    p += (size_t)N * 256 * 2;
    unsigned short* H = (unsigned short*)p;      p += (size_t)N * 256 * 2;
    unsigned short* xb = H;                      // alias (dead before H first write)
    unsigned short* xa = (unsigned short*)p;     p += (size_t)N * 128 * 2;
    float* dinv = (float*)p;                     p += (size_t)N * 4;
    int* cnt = (int*)p;                          p += (size_t)N * 4;
    int* offs = (int*)p;                         p += (size_t)(N + 1) * 4;
    int* cursor = (int*)p;                       p += (size_t)N * 4;
    int* partial = (int*)p;                      p += (size_t)N * 4;
    int* bsum = (int*)p;                         p += (size_t)nb * 4;
    int* bsumoff = (int*)p;                      p += (size_t)nb * 4;
    p = align16(p);
    unsigned short* W1T = (unsigned short*)p;    p += 256 * 128 * 2;   // [256][128]
    unsigned short* W2T = (unsigned short*)p;    p += 128 * 256 * 2;   // [128][256]
    unsigned short* W3T = (unsigned short*)p;    p += 64 * 128 * 2;    // [64][128]
    p = align16(p);
    int* csr_src = (int*)p;                      p += (size_t)E4 * 4;
    p = align16(p);
    float* csr_w = USEW ? (float*)p : nullptr;

    // CSR + norms
    k_zero_i32<<<nb, 256, 0, stream>>>(cnt, N);
    k_count<<<(E + 255) / 256, 256, 0, stream>>>(col, cnt, E, N);
    k_scan1<<<nb, 256, 0, stream>>>(cnt, partial, bsum, N);
    k_scan2<<<1, 256, 0, stream>>>(bsum, bsumoff, nb);
    k_scan3<<<nb, 256, 0, stream>>>(partial, bsumoff, cnt, offs, cursor, dinv, N);
    k_fill<<<(E + 255) / 256, 256, 0, stream>>>(row, col, cursor, dinv, csr_src, csr_w, E, N, E4);
    k_pad<<<nb, 256, 0, stream>>>(cnt, offs, cursor, csr_src, csr_w, N);

    // weight casts (bf16, transposed)
    k_wcast<<<(128 * 256 + 255) / 256, 256, 0, stream>>>(W1, W1T, 128, 256);
    k_wcast<<<(256 * 128 + 255) / 256, 256, 0, stream>>>(W2, W2T, 256, 128);
    k_wcast<<<(128 * 64 + 255) / 256, 256, 0, stream>>>(W3, W3T, 128, 64);

    const int gx = (N + 127) / 128;
    // layer 1: act1 = relu( (Â x) W1 + b1 )
    k_cvt_bf<<<(unsigned)(((size_t)N * 128 + 255) / 256), 256, 0, stream>>>(x, xb, (size_t)N * 128);
    k_aggb<128, false, false, USEW><<<(unsigned)(((size_t)N * 64 + 255) / 256), 256, 0, stream>>>(xb, xa, offs, csr_src, csr_w, dinv, nullptr, N, E4);
    k_gemm_mfma<128, 256, true><<<dim3(gx, 2), 256, 0, stream>>>(xa, W1T, act, b1, N, 128);
    // layer 2
    k_gemm_mfma<128, 128, false><<<dim3(gx, 1), 256, 0, stream>>>(act, W2T, H, nullptr, N, 256);
    k_aggb<128, true, true, USEW><<<(unsigned)(((size_t)N * 64 + 255) / 256), 256, 0, stream>>>(H, act, offs, csr_src, csr_w, dinv, b2, N, E4);
    // layer 3
    k_gemm_mfma<64, 64, false><<<dim3(gx, 1), 256, 0, stream>>>(act, W3T, H, nullptr, N, 128);
    k_aggb<64, true, true, USEW><<<(unsigned)(((size_t)N * 32 + 255) / 256), 256, 0, stream>>>(H, act, offs, csr_src, csr_w, dinv, b3, N, E4);
    // layer 4
    k_gemm32<<<(N + 31) / 32, 256, 0, stream>>>(act, W4, H, N);
    k_aggb<32, true, true, USEW><<<(unsigned)(((size_t)N * 16 + 255) / 256), 256, 0, stream>>>(H, act, offs, csr_src, csr_w, dinv, b4, N, E4);
    // fused heads
    float* outF = (float*)d_out;
    k_gemm_heads<<<(unsigned)(((size_t)N * 32 + 255) / 256), 256, 0, stream>>>(act, Wmu, Wls, H, N);
    k_agg_heads<USEW><<<(unsigned)(((size_t)N * 16 + 255) / 256), 256, 0, stream>>>(H, outF, offs, csr_src, csr_w, dinv, bmu, bls, N, E4);
}

extern "C" void kernel_launch(void* const* d_in, const int* in_sizes, int n_in,
                              void* d_out, int out_size, void* d_ws, size_t ws_size,
                              hipStream_t stream) {
    const int N = in_sizes[0] / 128;
    const int E = in_sizes[1] / 2;
    const int nb = (N + 255) / 256;
    const size_t E4 = (size_t)E + 4 * (size_t)N;

    size_t fixed = (size_t)N * 256 * 2 * 2 + (size_t)N * 128 * 2
                 + (size_t)N * 4 * 5 + 4 + (size_t)nb * 8
                 + (256 * 128 + 128 * 256 + 64 * 128) * 2 + 96;
    size_t need_w = fixed + E4 * 8;
    if (ws_size >= need_w)
        run_pipeline<true>(d_in, d_out, d_ws, N, E, stream);
    else
        run_pipeline<false>(d_in, d_out, d_ws, N, E, stream);
}

// Round 13
// 393.253 us; speedup vs baseline: 2.7314x; 1.0109x over previous
//
#include <hip/hip_runtime.h>
#include <hip/hip_bf16.h>
#include <stdint.h>

__device__ inline int imin(int a, int b) { return a < b ? a : b; }
__device__ inline int imax(int a, int b) { return a > b ? a : b; }
__device__ inline float bf2f(unsigned short u) {
    return __uint_as_float(((unsigned int)u) << 16);
}
__device__ inline unsigned short f2bf(float v) {
    unsigned int u = __float_as_uint(v);
    unsigned int r = u + 0x7FFFu + ((u >> 16) & 1u);
    return (unsigned short)(r >> 16);
}

typedef __attribute__((ext_vector_type(8))) short short8;   // 8 bf16 = 4 VGPRs
typedef __attribute__((ext_vector_type(4))) float floatx4;  // MFMA C/D

// ---------------- CSR build (padded-to-4 segments) ----------------

__global__ void k_zero_i32(int* __restrict__ p, int n) {
    int i = blockIdx.x * blockDim.x + threadIdx.x;
    if (i < n) p[i] = 0;
}

__global__ void k_count(const int* __restrict__ col, int* __restrict__ cnt, int E, int n) {
    int e = blockIdx.x * blockDim.x + threadIdx.x;
    if (e < E) {
        int c = imax(0, imin(col[e], n - 1));
        atomicAdd(&cnt[c], 1);
    }
}

__global__ __launch_bounds__(256) void k_scan1(const int* __restrict__ cnt,
                                               int* __restrict__ partial,
                                               int* __restrict__ bsum, int n) {
    __shared__ int tmp[256];
    int i = blockIdx.x * 256 + threadIdx.x;
    int v = (i < n) ? ((cnt[i] + 3) & ~3) : 0;
    tmp[threadIdx.x] = v;
    __syncthreads();
    #pragma unroll
    for (int s = 1; s < 256; s <<= 1) {
        int t = (threadIdx.x >= s) ? tmp[threadIdx.x - s] : 0;
        __syncthreads();
        tmp[threadIdx.x] += t;
        __syncthreads();
    }
    if (i < n) partial[i] = tmp[threadIdx.x] - v;
    if (threadIdx.x == 255) bsum[blockIdx.x] = tmp[255];
}

__global__ __launch_bounds__(256) void k_scan2(const int* __restrict__ bsum,
                                               int* __restrict__ bsumoff, int nb) {
    __shared__ int tmp[256];
    __shared__ int carry;
    if (threadIdx.x == 0) carry = 0;
    __syncthreads();
    for (int base = 0; base < nb; base += 256) {
        int i = base + threadIdx.x;
        int v = (i < nb) ? bsum[i] : 0;
        tmp[threadIdx.x] = v;
        __syncthreads();
        #pragma unroll
        for (int s = 1; s < 256; s <<= 1) {
            int t = (threadIdx.x >= s) ? tmp[threadIdx.x - s] : 0;
            __syncthreads();
            tmp[threadIdx.x] += t;
            __syncthreads();
        }
        if (i < nb) bsumoff[i] = carry + tmp[threadIdx.x] - v;
        __syncthreads();
        if (threadIdx.x == 0) carry += tmp[255];
        __syncthreads();
    }
}

__global__ __launch_bounds__(256) void k_scan3(const int* __restrict__ partial,
                                               const int* __restrict__ bsumoff,
                                               const int* __restrict__ cnt,
                                               int* __restrict__ offs, int* __restrict__ cursor,
                                               float* __restrict__ dinv, int n) {
    int i = blockIdx.x * 256 + threadIdx.x;
    if (i >= n) return;
    int v = partial[i] + bsumoff[blockIdx.x];
    offs[i] = v;
    cursor[i] = v;
    if (i == n - 1) offs[n] = v + ((cnt[i] + 3) & ~3);
    float d = (float)imax(cnt[i], 0) + 1.0f;
    dinv[i] = rsqrtf(d);
}

// USEW: AoS {src, w} 8B records (one random cacheline per edge); else src-only ints.
template <bool USEW>
__global__ void k_fill(const int* __restrict__ row, const int* __restrict__ col,
                       int* __restrict__ cursor, const float* __restrict__ dinv,
                       uint2* __restrict__ edges, int* __restrict__ csr_src,
                       int E, int n, int cap) {
    int e = blockIdx.x * blockDim.x + threadIdx.x;
    if (e >= E) return;
    int c = imax(0, imin(col[e], n - 1));
    int r = imax(0, imin(row[e], n - 1));
    int pos = atomicAdd(&cursor[c], 1);
    pos = imax(0, imin(pos, cap - 1));
    if (USEW) {
        uint2 rec;
        rec.x = (unsigned)r;
        rec.y = __float_as_uint(dinv[r]);
        edges[pos] = rec;
    } else {
        csr_src[pos] = r;
    }
}

template <bool USEW>
__global__ void k_pad(const int* __restrict__ cnt, const int* __restrict__ offs,
                      const int* __restrict__ cursor,
                      uint2* __restrict__ edges, int* __restrict__ csr_src, int n) {
    int i = blockIdx.x * blockDim.x + threadIdx.x;
    if (i >= n) return;
    int end = offs[i] + ((cnt[i] + 3) & ~3);
    for (int p = cursor[i]; p < end; p++) {
        if (USEW) edges[p] = make_uint2(0u, 0u);
        else csr_src[p] = 0;
    }
}

// ---------------- casts ----------------

__global__ void k_cvt_bf(const float* __restrict__ in, unsigned short* __restrict__ out, size_t n) {
    size_t i = (size_t)blockIdx.x * 256 + threadIdx.x;
    if (i < n) out[i] = f2bf(in[i]);
}

// fused: W1 [128][256] -> W1T [256][128]; W2 [256][128] -> W2T [128][256]; W3 [128][64] -> W3T [64][128]
__global__ void k_wcast3(const float* __restrict__ W1, unsigned short* __restrict__ W1T,
                         const float* __restrict__ W2, unsigned short* __restrict__ W2T,
                         const float* __restrict__ W3, unsigned short* __restrict__ W3T) {
    int idx = blockIdx.x * 256 + threadIdx.x;
    const int n1 = 128 * 256, n2 = 256 * 128, n3 = 128 * 64;
    if (idx < n1) {
        int k = idx >> 8, n = idx & 255;                  // W1: K=128, Nc=256
        W1T[n * 128 + k] = f2bf(W1[idx]);
    } else if (idx < n1 + n2) {
        int j = idx - n1;
        int k = j >> 7, n = j & 127;                      // W2: K=256, Nc=128
        W2T[n * 256 + k] = f2bf(W2[j]);
    } else if (idx < n1 + n2 + n3) {
        int j = idx - n1 - n2;
        int k = j >> 6, n = j & 63;                       // W3: K=128, Nc=64
        W3T[n * 128 + k] = f2bf(W3[j]);
    }
}

// ---------------- MFMA GEMM: H = act(bf16) @ W(bf16 WT), fp32 acc, bf16 out ----------------
// block: 128 rows x NT cols; wave w = rows w*32..w*32+31 (2 row-tiles of 16).
// LDS rows stride 40 shorts (80 B) -> 2-way bank aliasing only (free).
// Verified layouts: A[m=lane&15][k=quad*8+j]; B[k][n=lane&15]; C/D row=quad*4+reg, col=lane&15.

template <int NT, int FOUT, bool EPI>
__global__ __launch_bounds__(256) void k_gemm_mfma(const unsigned short* __restrict__ act,
                                                   const unsigned short* __restrict__ WT,
                                                   unsigned short* __restrict__ H,
                                                   const float* __restrict__ bias,
                                                   int nrows, int Fin) {
    constexpr int CT = NT / 16;
    __shared__ __align__(16) unsigned short sA[128 * 40];
    __shared__ __align__(16) unsigned short sB[NT * 40];
    const int tid = threadIdx.x;
    const int w = tid >> 6;
    const int lane = tid & 63;
    const int quad = lane >> 4;
    const int l15 = lane & 15;
    const int row0 = blockIdx.x * 128;
    const int col0 = blockIdx.y * NT;

    floatx4 acc[2][CT] = {};

    const int sr = tid >> 1;
    const int sp = (tid & 1) * 16;

    for (int k0 = 0; k0 < Fin; k0 += 32) {
        __syncthreads();
        {
            int grow = row0 + sr;
            uint4 v0 = make_uint4(0, 0, 0, 0), v1 = make_uint4(0, 0, 0, 0);
            if (grow < nrows) {
                const uint4* ap = (const uint4*)&act[(size_t)grow * Fin + k0 + sp];
                v0 = ap[0]; v1 = ap[1];
            }
            uint4* dst = (uint4*)&sA[sr * 40 + sp];
            dst[0] = v0; dst[1] = v1;
        }
        if (NT == 128 || tid < 128) {
            const uint4* wp = (const uint4*)&WT[(size_t)(col0 + sr) * Fin + k0 + sp];
            uint4* dst = (uint4*)&sB[sr * 40 + sp];
            dst[0] = wp[0]; dst[1] = wp[1];
        }
        __syncthreads();

        short8 bfr[CT];
        #pragma unroll
        for (int ct = 0; ct < CT; ct++)
            bfr[ct] = *(const short8*)&sB[(ct * 16 + l15) * 40 + quad * 8];
        #pragma unroll
        for (int rt = 0; rt < 2; rt++) {
            short8 afr = *(const short8*)&sA[(w * 32 + rt * 16 + l15) * 40 + quad * 8];
            #pragma unroll
            for (int ct = 0; ct < CT; ct++)
                acc[rt][ct] = __builtin_amdgcn_mfma_f32_16x16x32_bf16(afr, bfr[ct], acc[rt][ct], 0, 0, 0);
        }
    }

    #pragma unroll
    for (int rt = 0; rt < 2; rt++) {
        #pragma unroll
        for (int ct = 0; ct < CT; ct++) {
            int gcol = col0 + ct * 16 + l15;
            #pragma unroll
            for (int r = 0; r < 4; r++) {
                int grow = row0 + w * 32 + rt * 16 + quad * 4 + r;
                if (grow < nrows) {
                    float v = acc[rt][ct][r];
                    if (EPI) v = fmaxf(v + bias[gcol], 0.f);
                    H[(size_t)grow * FOUT + gcol] = f2bf(v);
                }
            }
        }
    }
}

// ---------------- small GEMMs (bf16 act in, bf16 out) ----------------

__global__ __launch_bounds__(256) void k_gemm32(const unsigned short* __restrict__ act,
                                                const float* __restrict__ W,
                                                unsigned short* __restrict__ H,
                                                int nrows) {
    __shared__ __align__(16) float sA[32 * 68];
    __shared__ __align__(16) float sW[16 * 32];
    const int tid = threadIdx.x;
    const int row0 = blockIdx.x * 32;
    const int Fin = 64, strA = 68;

    for (int i = tid; i < 32 * Fin; i += 256) {
        int r = i >> 6;
        int k = i & 63;
        float v = 0.f;
        if (row0 + r < nrows) v = bf2f(act[(size_t)row0 * Fin + i]);
        sA[r * strA + k] = v;
    }

    const int rl = tid >> 3;
    const int cg = tid & 7;
    float a0 = 0.f, a1 = 0.f, a2 = 0.f, a3 = 0.f;

    for (int k0 = 0; k0 < Fin; k0 += 16) {
        __syncthreads();
        const float* wsrc = W + (size_t)k0 * 32;
        for (int i = tid; i < 16 * 32; i += 256) sW[i] = wsrc[i];
        __syncthreads();
        #pragma unroll 4
        for (int kk = 0; kk < 16; kk++) {
            float a = sA[rl * strA + k0 + kk];
            float4 wv = *(const float4*)&sW[kk * 32 + cg * 4];
            a0 = fmaf(a, wv.x, a0);
            a1 = fmaf(a, wv.y, a1);
            a2 = fmaf(a, wv.z, a2);
            a3 = fmaf(a, wv.w, a3);
        }
    }

    const int rowi = row0 + rl;
    if (rowi < nrows) {
        unsigned short* hp = &H[(size_t)rowi * 32 + cg * 4];
        hp[0] = f2bf(a0); hp[1] = f2bf(a1); hp[2] = f2bf(a2); hp[3] = f2bf(a3);
    }
}

__global__ void k_gemm_heads(const unsigned short* __restrict__ act,
                             const float* __restrict__ Wmu, const float* __restrict__ Wls,
                             unsigned short* __restrict__ H, int nrows) {
    int idx = blockIdx.x * blockDim.x + threadIdx.x;
    if (idx >= nrows * 32) return;
    int r = idx >> 5;
    int c = idx & 31;
    const float* Wp = (c < 16) ? Wmu : Wls;
    int cc = c & 15;
    float acc = 0.f;
    #pragma unroll 8
    for (int k = 0; k < 32; k++)
        acc = fmaf(bf2f(act[(size_t)r * 32 + k]), Wp[k * 16 + cc], acc);
    H[idx] = f2bf(acc);
}

// ---- aggregation over bf16 H, 4x-unrolled padded CSR; bf16 out ----

template <int F, bool RELU, bool HASBIAS, bool USEW>
__global__ __launch_bounds__(256) void k_aggb(const unsigned short* __restrict__ Hb,
                                              unsigned short* __restrict__ out,
                                              const int* __restrict__ offs,
                                              const uint2* __restrict__ edges,
                                              const int* __restrict__ src,
                                              const float* __restrict__ dinv,
                                              const float* __restrict__ bias,
                                              int nnodes, int Ecap) {
    constexpr int TPN = (F >= 128) ? 64 : F / 2;
    int t = blockIdx.x * 256 + threadIdx.x;
    int node = t / TPN;
    int ln = t % TPN;
    if (node >= nnodes) return;
    int f0 = 2 * ln;

    float di = dinv[node];
    ushort2 sv = *(const ushort2*)&Hb[(size_t)node * F + f0];
    float acc0 = di * bf2f(sv.x);
    float acc1 = di * bf2f(sv.y);

    int s0 = offs[node];
    int s1 = offs[node + 1];
    s0 = imax(0, imin(s0, Ecap));
    s1 = imax(s0, imin(s1, Ecap));
    for (int e = s0; e < s1; e += 4) {
        int sr0, sr1, sr2, sr3;
        float w0, w1, w2, w3;
        if (USEW) {
            uint4 p0 = *(const uint4*)(edges + e);
            uint4 p1 = *(const uint4*)(edges + e + 2);
            sr0 = (int)p0.x; w0 = __uint_as_float(p0.y);
            sr1 = (int)p0.z; w1 = __uint_as_float(p0.w);
            sr2 = (int)p1.x; w2 = __uint_as_float(p1.y);
            sr3 = (int)p1.z; w3 = __uint_as_float(p1.w);
        } else {
            const int4 sr4 = *(const int4*)(src + e);
            sr0 = sr4.x; sr1 = sr4.y; sr2 = sr4.z; sr3 = sr4.w;
            w0 = dinv[sr0]; w1 = dinv[sr1]; w2 = dinv[sr2]; w3 = dinv[sr3];
        }
        ushort2 h0 = *(const ushort2*)&Hb[(size_t)sr0 * F + f0];
        ushort2 h1 = *(const ushort2*)&Hb[(size_t)sr1 * F + f0];
        ushort2 h2 = *(const ushort2*)&Hb[(size_t)sr2 * F + f0];
        ushort2 h3 = *(const ushort2*)&Hb[(size_t)sr3 * F + f0];
        acc0 = fmaf(w0, bf2f(h0.x), acc0);
        acc1 = fmaf(w0, bf2f(h0.y), acc1);
        acc0 = fmaf(w1, bf2f(h1.x), acc0);
        acc1 = fmaf(w1, bf2f(h1.y), acc1);
        acc0 = fmaf(w2, bf2f(h2.x), acc0);
        acc1 = fmaf(w2, bf2f(h2.y), acc1);
        acc0 = fmaf(w3, bf2f(h3.x), acc0);
        acc1 = fmaf(w3, bf2f(h3.y), acc1);
    }
    float v0 = di * acc0;
    float v1 = di * acc1;
    if (HASBIAS) { v0 += bias[f0]; v1 += bias[f0 + 1]; }
    if (RELU) { v0 = fmaxf(v0, 0.f); v1 = fmaxf(v1, 0.f); }
    ushort2 o; o.x = f2bf(v0); o.y = f2bf(v1);
    *(ushort2*)&out[(size_t)node * F + f0] = o;
}

// fused heads aggregation: F=32 (mu 0..15, logstd 16..31), fp32 split output to d_out
template <bool USEW>
__global__ __launch_bounds__(256) void k_agg_heads(const unsigned short* __restrict__ Hb,
                                                   float* __restrict__ out,
                                                   const int* __restrict__ offs,
                                                   const uint2* __restrict__ edges,
                                                   const int* __restrict__ src,
                                                   const float* __restrict__ dinv,
                                                   const float* __restrict__ bmu, const float* __restrict__ bls,
                                                   int nnodes, int Ecap) {
    constexpr int F = 32, TPN = 16;
    int t = blockIdx.x * 256 + threadIdx.x;
    int node = t / TPN;
    int ln = t % TPN;
    if (node >= nnodes) return;
    int f0 = 2 * ln;

    float di = dinv[node];
    ushort2 sv = *(const ushort2*)&Hb[(size_t)node * F + f0];
    float acc0 = di * bf2f(sv.x);
    float acc1 = di * bf2f(sv.y);

    int s0 = offs[node];
    int s1 = offs[node + 1];
    s0 = imax(0, imin(s0, Ecap));
    s1 = imax(s0, imin(s1, Ecap));
    for (int e = s0; e < s1; e += 4) {
        int sr0, sr1, sr2, sr3;
        float w0, w1, w2, w3;
        if (USEW) {
            uint4 p0 = *(const uint4*)(edges + e);
            uint4 p1 = *(const uint4*)(edges + e + 2);
            sr0 = (int)p0.x; w0 = __uint_as_float(p0.y);
            sr1 = (int)p0.z; w1 = __uint_as_float(p0.w);
            sr2 = (int)p1.x; w2 = __uint_as_float(p1.y);
            sr3 = (int)p1.z; w3 = __uint_as_float(p1.w);
        } else {
            const int4 sr4 = *(const int4*)(src + e);
            sr0 = sr4.x; sr1 = sr4.y; sr2 = sr4.z; sr3 = sr4.w;
            w0 = dinv[sr0]; w1 = dinv[sr1]; w2 = dinv[sr2]; w3 = dinv[sr3];
        }
        ushort2 h0 = *(const ushort2*)&Hb[(size_t)sr0 * F + f0];
        ushort2 h1 = *(const ushort2*)&Hb[(size_t)sr1 * F + f0];
        ushort2 h2 = *(const ushort2*)&Hb[(size_t)sr2 * F + f0];
        ushort2 h3 = *(const ushort2*)&Hb[(size_t)sr3 * F + f0];
        acc0 = fmaf(w0, bf2f(h0.x), acc0);
        acc1 = fmaf(w0, bf2f(h0.y), acc1);
        acc0 = fmaf(w1, bf2f(h1.x), acc0);
        acc1 = fmaf(w1, bf2f(h1.y), acc1);
        acc0 = fmaf(w2, bf2f(h2.x), acc0);
        acc1 = fmaf(w2, bf2f(h2.y), acc1);
        acc0 = fmaf(w3, bf2f(h3.x), acc0);
        acc1 = fmaf(w3, bf2f(h3.y), acc1);
    }
    const float* bp = (f0 < 16) ? bmu : bls;
    int fb = f0 & 15;
    float v0 = fmaf(di, acc0, bp[fb]);
    float v1 = fmaf(di, acc1, bp[fb + 1]);
    float* op = (f0 < 16) ? (out + (size_t)node * 16 + fb)
                          : (out + (size_t)nnodes * 16 + (size_t)node * 16 + fb);
    *(float2*)op = make_float2(v0, v1);
}

// ---------------- pipeline ----------------

template <bool USEW>
static void run_pipeline(void* const* d_in, void* d_out, void* d_ws,
                         int N, int E, hipStream_t stream) {
    const float* x  = (const float*)d_in[0];
    const int* ei   = (const int*)d_in[1];
    const float* W1 = (const float*)d_in[2];
    const float* b1 = (const float*)d_in[3];
    const float* W2 = (const float*)d_in[4];
    const float* b2 = (const float*)d_in[5];
    const float* W3 = (const float*)d_in[6];
    const float* b3 = (const float*)d_in[7];
    const float* W4 = (const float*)d_in[8];
    const float* b4 = (const float*)d_in[9];
    const float* Wmu = (const float*)d_in[10];
    const float* bmu = (const float*)d_in[11];
    const float* Wls = (const float*)d_in[12];
    const float* bls = (const float*)d_in[13];
    const int* row = ei;        // edge_index[0] = source
    const int* col = ei + E;    // edge_index[1] = target
    const int nb = (N + 255) / 256;
    const int E4 = E + 4 * N;

    auto align16 = [](char* p) {
        return (char*)(((uintptr_t)p + 15) & ~(uintptr_t)15);
    };
    char* p = (char*)d_ws;
    unsigned short* act = (unsigned short*)p;    p += (size_t)N * 256 * 2;
    unsigned short* H = (unsigned short*)p;      p += (size_t)N * 256 * 2;
    unsigned short* xb = H;                      // alias (dead before H first write)
    unsigned short* xa = (unsigned short*)p;     p += (size_t)N * 128 * 2;
    float* dinv = (float*)p;                     p += (size_t)N * 4;
    int* cnt = (int*)p;                          p += (size_t)N * 4;
    int* offs = (int*)p;                         p += (size_t)(N + 1) * 4;
    int* cursor = (int*)p;                       p += (size_t)N * 4;
    int* partial = (int*)p;                      p += (size_t)N * 4;
    int* bsum = (int*)p;                         p += (size_t)nb * 4;
    int* bsumoff = (int*)p;                      p += (size_t)nb * 4;
    p = align16(p);
    unsigned short* W1T = (unsigned short*)p;    p += 256 * 128 * 2;
    unsigned short* W2T = (unsigned short*)p;    p += 128 * 256 * 2;
    unsigned short* W3T = (unsigned short*)p;    p += 64 * 128 * 2;
    p = align16(p);
    uint2* edges = nullptr;
    int* csr_src = nullptr;
    if (USEW) edges = (uint2*)p;
    else      csr_src = (int*)p;

    // CSR + norms
    k_zero_i32<<<nb, 256, 0, stream>>>(cnt, N);
    k_count<<<(E + 255) / 256, 256, 0, stream>>>(col, cnt, E, N);
    k_scan1<<<nb, 256, 0, stream>>>(cnt, partial, bsum, N);
    k_scan2<<<1, 256, 0, stream>>>(bsum, bsumoff, nb);
    k_scan3<<<nb, 256, 0, stream>>>(partial, bsumoff, cnt, offs, cursor, dinv, N);
    k_fill<USEW><<<(E + 255) / 256, 256, 0, stream>>>(row, col, cursor, dinv, edges, csr_src, E, N, E4);
    k_pad<USEW><<<nb, 256, 0, stream>>>(cnt, offs, cursor, edges, csr_src, N);

    // weight casts (bf16, transposed), fused
    k_wcast3<<<(128 * 256 + 256 * 128 + 128 * 64 + 255) / 256, 256, 0, stream>>>(W1, W1T, W2, W2T, W3, W3T);

    const int gx = (N + 127) / 128;
    // layer 1: act1 = relu( (Â x) W1 + b1 )
    k_cvt_bf<<<(unsigned)(((size_t)N * 128 + 255) / 256), 256, 0, stream>>>(x, xb, (size_t)N * 128);
    k_aggb<128, false, false, USEW><<<(unsigned)(((size_t)N * 64 + 255) / 256), 256, 0, stream>>>(xb, xa, offs, edges, csr_src, dinv, nullptr, N, E4);
    k_gemm_mfma<128, 256, true><<<dim3(gx, 2), 256, 0, stream>>>(xa, W1T, act, b1, N, 128);
    // layer 2
    k_gemm_mfma<128, 128, false><<<dim3(gx, 1), 256, 0, stream>>>(act, W2T, H, nullptr, N, 256);
    k_aggb<128, true, true, USEW><<<(unsigned)(((size_t)N * 64 + 255) / 256), 256, 0, stream>>>(H, act, offs, edges, csr_src, dinv, b2, N, E4);
    // layer 3
    k_gemm_mfma<64, 64, false><<<dim3(gx, 1), 256, 0, stream>>>(act, W3T, H, nullptr, N, 128);
    k_aggb<64, true, true, USEW><<<(unsigned)(((size_t)N * 32 + 255) / 256), 256, 0, stream>>>(H, act, offs, edges, csr_src, dinv, b3, N, E4);
    // layer 4
    k_gemm32<<<(N + 31) / 32, 256, 0, stream>>>(act, W4, H, N);
    k_aggb<32, true, true, USEW><<<(unsigned)(((size_t)N * 16 + 255) / 256), 256, 0, stream>>>(H, act, offs, edges, csr_src, dinv, b4, N, E4);
    // fused heads
    float* outF = (float*)d_out;
    k_gemm_heads<<<(unsigned)(((size_t)N * 32 + 255) / 256), 256, 0, stream>>>(act, Wmu, Wls, H, N);
    k_agg_heads<USEW><<<(unsigned)(((size_t)N * 16 + 255) / 256), 256, 0, stream>>>(H, outF, offs, edges, csr_src, dinv, bmu, bls, N, E4);
}

extern "C" void kernel_launch(void* const* d_in, const int* in_sizes, int n_in,
                              void* d_out, int out_size, void* d_ws, size_t ws_size,
                              hipStream_t stream) {
    const int N = in_sizes[0] / 128;
    const int E = in_sizes[1] / 2;
    const int nb = (N + 255) / 256;
    const size_t E4 = (size_t)E + 4 * (size_t)N;

    size_t fixed = (size_t)N * 256 * 2 * 2 + (size_t)N * 128 * 2
                 + (size_t)N * 4 * 5 + 4 + (size_t)nb * 8
                 + (256 * 128 + 128 * 256 + 64 * 128) * 2 + 96;
    size_t need_w = fixed + E4 * 8;
    if (ws_size >= need_w)
        run_pipeline<true>(d_in, d_out, d_ws, N, E, stream);
    else
        run_pipeline<false>(d_in, d_out, d_ws, N, E, stream);
}

// Round 14
// 382.136 us; speedup vs baseline: 2.8109x; 1.0291x over previous
//
#include <hip/hip_runtime.h>
#include <hip/hip_bf16.h>
#include <stdint.h>

__device__ inline int imin(int a, int b) { return a < b ? a : b; }
__device__ inline int imax(int a, int b) { return a > b ? a : b; }
__device__ inline float bf2f(unsigned short u) {
    return __uint_as_float(((unsigned int)u) << 16);
}
__device__ inline unsigned short f2bf(float v) {
    unsigned int u = __float_as_uint(v);
    unsigned int r = u + 0x7FFFu + ((u >> 16) & 1u);
    return (unsigned short)(r >> 16);
}

typedef __attribute__((ext_vector_type(8))) short short8;   // 8 bf16 = 4 VGPRs
typedef __attribute__((ext_vector_type(4))) float floatx4;  // MFMA C/D

// ---------------- prologue: zero cnt + cast x->bf16 + weight casts ----------------

__global__ void k_prologue(int* __restrict__ cnt, int n,
                           const float* __restrict__ x, unsigned short* __restrict__ xb, size_t nx,
                           const float* __restrict__ W1, unsigned short* __restrict__ W1T,
                           const float* __restrict__ W2, unsigned short* __restrict__ W2T,
                           const float* __restrict__ W3, unsigned short* __restrict__ W3T) {
    size_t i = (size_t)blockIdx.x * 256 + threadIdx.x;
    if (i < (size_t)n) { cnt[i] = 0; }
    size_t j = i - n;
    if (i >= (size_t)n && j < nx) { xb[j] = f2bf(x[j]); }
    size_t k = j - nx;
    const int n1 = 128 * 256, n2 = 256 * 128, n3 = 128 * 64;
    if (j >= nx && k < (size_t)(n1 + n2 + n3)) {
        int idx = (int)k;
        if (idx < n1) {
            int kk = idx >> 8, nn = idx & 255;            // W1: K=128, Nc=256
            W1T[nn * 128 + kk] = f2bf(W1[idx]);
        } else if (idx < n1 + n2) {
            int jj = idx - n1;
            int kk = jj >> 7, nn = jj & 127;              // W2: K=256, Nc=128
            W2T[nn * 256 + kk] = f2bf(W2[jj]);
        } else {
            int jj = idx - n1 - n2;
            int kk = jj >> 6, nn = jj & 63;               // W3: K=128, Nc=64
            W3T[nn * 128 + kk] = f2bf(W3[jj]);
        }
    }
}

// ---------------- CSR build (padded-to-8 segments) ----------------

__global__ void k_count(const int* __restrict__ col, int* __restrict__ cnt, int E, int n) {
    int e0 = (blockIdx.x * blockDim.x + threadIdx.x) * 2;
    if (e0 < E) {
        int c = imax(0, imin(col[e0], n - 1));
        atomicAdd(&cnt[c], 1);
    }
    if (e0 + 1 < E) {
        int c = imax(0, imin(col[e0 + 1], n - 1));
        atomicAdd(&cnt[c], 1);
    }
}

__global__ __launch_bounds__(256) void k_scan1(const int* __restrict__ cnt,
                                               int* __restrict__ partial,
                                               int* __restrict__ bsum, int n) {
    __shared__ int tmp[256];
    int i = blockIdx.x * 256 + threadIdx.x;
    int v = (i < n) ? ((cnt[i] + 7) & ~7) : 0;
    tmp[threadIdx.x] = v;
    __syncthreads();
    #pragma unroll
    for (int s = 1; s < 256; s <<= 1) {
        int t = (threadIdx.x >= s) ? tmp[threadIdx.x - s] : 0;
        __syncthreads();
        tmp[threadIdx.x] += t;
        __syncthreads();
    }
    if (i < n) partial[i] = tmp[threadIdx.x] - v;
    if (threadIdx.x == 255) bsum[blockIdx.x] = tmp[255];
}

__global__ __launch_bounds__(256) void k_scan2(const int* __restrict__ bsum,
                                               int* __restrict__ bsumoff, int nb) {
    __shared__ int tmp[256];
    __shared__ int carry;
    if (threadIdx.x == 0) carry = 0;
    __syncthreads();
    for (int base = 0; base < nb; base += 256) {
        int i = base + threadIdx.x;
        int v = (i < nb) ? bsum[i] : 0;
        tmp[threadIdx.x] = v;
        __syncthreads();
        #pragma unroll
        for (int s = 1; s < 256; s <<= 1) {
            int t = (threadIdx.x >= s) ? tmp[threadIdx.x - s] : 0;
            __syncthreads();
            tmp[threadIdx.x] += t;
            __syncthreads();
        }
        if (i < nb) bsumoff[i] = carry + tmp[threadIdx.x] - v;
        __syncthreads();
        if (threadIdx.x == 0) carry += tmp[255];
        __syncthreads();
    }
}

__global__ __launch_bounds__(256) void k_scan3(const int* __restrict__ partial,
                                               const int* __restrict__ bsumoff,
                                               const int* __restrict__ cnt,
                                               int* __restrict__ offs, int* __restrict__ cursor,
                                               float* __restrict__ dinv, int n) {
    int i = blockIdx.x * 256 + threadIdx.x;
    if (i >= n) return;
    int v = partial[i] + bsumoff[blockIdx.x];
    offs[i] = v;
    cursor[i] = v;
    if (i == n - 1) offs[n] = v + ((cnt[i] + 7) & ~7);
    float d = (float)imax(cnt[i], 0) + 1.0f;
    dinv[i] = rsqrtf(d);
}

// AoS {src, w} 8B records; 2 edges/thread for store-level ILP.
template <bool USEW>
__global__ void k_fill(const int* __restrict__ row, const int* __restrict__ col,
                       int* __restrict__ cursor, const float* __restrict__ dinv,
                       uint2* __restrict__ edges, int* __restrict__ csr_src,
                       int E, int n, int cap) {
    int e0 = (blockIdx.x * blockDim.x + threadIdx.x) * 2;
    #pragma unroll
    for (int u = 0; u < 2; u++) {
        int e = e0 + u;
        if (e >= E) break;
        int c = imax(0, imin(col[e], n - 1));
        int r = imax(0, imin(row[e], n - 1));
        int pos = atomicAdd(&cursor[c], 1);
        pos = imax(0, imin(pos, cap - 1));
        if (USEW) {
            uint2 rec;
            rec.x = (unsigned)r;
            rec.y = __float_as_uint(dinv[r]);
            edges[pos] = rec;
        } else {
            csr_src[pos] = r;
        }
    }
}

template <bool USEW>
__global__ void k_pad(const int* __restrict__ cnt, const int* __restrict__ offs,
                      const int* __restrict__ cursor,
                      uint2* __restrict__ edges, int* __restrict__ csr_src, int n) {
    int i = blockIdx.x * blockDim.x + threadIdx.x;
    if (i >= n) return;
    int end = offs[i] + ((cnt[i] + 7) & ~7);
    for (int p = cursor[i]; p < end; p++) {
        if (USEW) edges[p] = make_uint2(0u, 0u);
        else csr_src[p] = 0;
    }
}

// ---------------- MFMA GEMM: H = act(bf16) @ W(bf16 WT), fp32 acc, bf16 out ----------------
// block: 128 rows x NT cols; wave w = rows w*32..w*32+31 (2 row-tiles of 16).
// LDS rows stride 40 shorts (80 B) -> 2-way bank aliasing only (free).
// Verified layouts: A[m=lane&15][k=quad*8+j]; B[k][n=lane&15]; C/D row=quad*4+reg, col=lane&15.

template <int NT, int FOUT, bool EPI>
__global__ __launch_bounds__(256) void k_gemm_mfma(const unsigned short* __restrict__ act,
                                                   const unsigned short* __restrict__ WT,
                                                   unsigned short* __restrict__ H,
                                                   const float* __restrict__ bias,
                                                   int nrows, int Fin) {
    constexpr int CT = NT / 16;
    __shared__ __align__(16) unsigned short sA[128 * 40];
    __shared__ __align__(16) unsigned short sB[NT * 40];
    const int tid = threadIdx.x;
    const int w = tid >> 6;
    const int lane = tid & 63;
    const int quad = lane >> 4;
    const int l15 = lane & 15;
    const int row0 = blockIdx.x * 128;
    const int col0 = blockIdx.y * NT;

    floatx4 acc[2][CT] = {};

    const int sr = tid >> 1;
    const int sp = (tid & 1) * 16;

    for (int k0 = 0; k0 < Fin; k0 += 32) {
        __syncthreads();
        {
            int grow = row0 + sr;
            uint4 v0 = make_uint4(0, 0, 0, 0), v1 = make_uint4(0, 0, 0, 0);
            if (grow < nrows) {
                const uint4* ap = (const uint4*)&act[(size_t)grow * Fin + k0 + sp];
                v0 = ap[0]; v1 = ap[1];
            }
            uint4* dst = (uint4*)&sA[sr * 40 + sp];
            dst[0] = v0; dst[1] = v1;
        }
        if (NT == 128 || tid < 128) {
            const uint4* wp = (const uint4*)&WT[(size_t)(col0 + sr) * Fin + k0 + sp];
            uint4* dst = (uint4*)&sB[sr * 40 + sp];
            dst[0] = wp[0]; dst[1] = wp[1];
        }
        __syncthreads();

        short8 bfr[CT];
        #pragma unroll
        for (int ct = 0; ct < CT; ct++)
            bfr[ct] = *(const short8*)&sB[(ct * 16 + l15) * 40 + quad * 8];
        #pragma unroll
        for (int rt = 0; rt < 2; rt++) {
            short8 afr = *(const short8*)&sA[(w * 32 + rt * 16 + l15) * 40 + quad * 8];
            #pragma unroll
            for (int ct = 0; ct < CT; ct++)
                acc[rt][ct] = __builtin_amdgcn_mfma_f32_16x16x32_bf16(afr, bfr[ct], acc[rt][ct], 0, 0, 0);
        }
    }

    #pragma unroll
    for (int rt = 0; rt < 2; rt++) {
        #pragma unroll
        for (int ct = 0; ct < CT; ct++) {
            int gcol = col0 + ct * 16 + l15;
            #pragma unroll
            for (int r = 0; r < 4; r++) {
                int grow = row0 + w * 32 + rt * 16 + quad * 4 + r;
                if (grow < nrows) {
                    float v = acc[rt][ct][r];
                    if (EPI) v = fmaxf(v + bias[gcol], 0.f);
                    H[(size_t)grow * FOUT + gcol] = f2bf(v);
                }
            }
        }
    }
}

// ---------------- small GEMMs (bf16 act in, bf16 out) ----------------

__global__ __launch_bounds__(256) void k_gemm32(const unsigned short* __restrict__ act,
                                                const float* __restrict__ W,
                                                unsigned short* __restrict__ H,
                                                int nrows) {
    __shared__ __align__(16) float sA[32 * 68];
    __shared__ __align__(16) float sW[16 * 32];
    const int tid = threadIdx.x;
    const int row0 = blockIdx.x * 32;
    const int Fin = 64, strA = 68;

    for (int i = tid; i < 32 * Fin; i += 256) {
        int r = i >> 6;
        int k = i & 63;
        float v = 0.f;
        if (row0 + r < nrows) v = bf2f(act[(size_t)row0 * Fin + i]);
        sA[r * strA + k] = v;
    }

    const int rl = tid >> 3;
    const int cg = tid & 7;
    float a0 = 0.f, a1 = 0.f, a2 = 0.f, a3 = 0.f;

    for (int k0 = 0; k0 < Fin; k0 += 16) {
        __syncthreads();
        const float* wsrc = W + (size_t)k0 * 32;
        for (int i = tid; i < 16 * 32; i += 256) sW[i] = wsrc[i];
        __syncthreads();
        #pragma unroll 4
        for (int kk = 0; kk < 16; kk++) {
            float a = sA[rl * strA + k0 + kk];
            float4 wv = *(const float4*)&sW[kk * 32 + cg * 4];
            a0 = fmaf(a, wv.x, a0);
            a1 = fmaf(a, wv.y, a1);
            a2 = fmaf(a, wv.z, a2);
            a3 = fmaf(a, wv.w, a3);
        }
    }

    const int rowi = row0 + rl;
    if (rowi < nrows) {
        unsigned short* hp = &H[(size_t)rowi * 32 + cg * 4];
        hp[0] = f2bf(a0); hp[1] = f2bf(a1); hp[2] = f2bf(a2); hp[3] = f2bf(a3);
    }
}

__global__ void k_gemm_heads(const unsigned short* __restrict__ act,
                             const float* __restrict__ Wmu, const float* __restrict__ Wls,
                             unsigned short* __restrict__ H, int nrows) {
    int idx = blockIdx.x * blockDim.x + threadIdx.x;
    if (idx >= nrows * 32) return;
    int r = idx >> 5;
    int c = idx & 31;
    const float* Wp = (c < 16) ? Wmu : Wls;
    int cc = c & 15;
    float acc = 0.f;
    #pragma unroll 8
    for (int k = 0; k < 32; k++)
        acc = fmaf(bf2f(act[(size_t)r * 32 + k]), Wp[k * 16 + cc], acc);
    H[idx] = f2bf(acc);
}

// ---- aggregation over bf16 H, 8x-unrolled padded CSR; bf16 out ----
// per edge block of 8: 4x uint4 edge reads + 8 independent H-row gathers in flight.

template <int F, bool RELU, bool HASBIAS, bool USEW>
__global__ __launch_bounds__(256) void k_aggb(const unsigned short* __restrict__ Hb,
                                              unsigned short* __restrict__ out,
                                              const int* __restrict__ offs,
                                              const uint2* __restrict__ edges,
                                              const int* __restrict__ src,
                                              const float* __restrict__ dinv,
                                              const float* __restrict__ bias,
                                              int nnodes, int Ecap) {
    constexpr int TPN = (F >= 128) ? 64 : F / 2;
    int t = blockIdx.x * 256 + threadIdx.x;
    int node = t / TPN;
    int ln = t % TPN;
    if (node >= nnodes) return;
    int f0 = 2 * ln;

    float di = dinv[node];
    ushort2 sv = *(const ushort2*)&Hb[(size_t)node * F + f0];
    float acc0 = di * bf2f(sv.x);
    float acc1 = di * bf2f(sv.y);

    int s0 = offs[node];
    int s1 = offs[node + 1];
    s0 = imax(0, imin(s0, Ecap));
    s1 = imax(s0, imin(s1, Ecap));
    for (int e = s0; e < s1; e += 8) {
        int sr[8];
        float wv[8];
        if (USEW) {
            #pragma unroll
            for (int q = 0; q < 4; q++) {
                uint4 pr = *(const uint4*)(edges + e + 2 * q);
                sr[2 * q] = (int)pr.x;     wv[2 * q] = __uint_as_float(pr.y);
                sr[2 * q + 1] = (int)pr.z; wv[2 * q + 1] = __uint_as_float(pr.w);
            }
        } else {
            int4 a = *(const int4*)(src + e);
            int4 b = *(const int4*)(src + e + 4);
            sr[0] = a.x; sr[1] = a.y; sr[2] = a.z; sr[3] = a.w;
            sr[4] = b.x; sr[5] = b.y; sr[6] = b.z; sr[7] = b.w;
            #pragma unroll
            for (int q = 0; q < 8; q++) wv[q] = dinv[sr[q]];
        }
        ushort2 h[8];
        #pragma unroll
        for (int q = 0; q < 8; q++)
            h[q] = *(const ushort2*)&Hb[(size_t)sr[q] * F + f0];
        #pragma unroll
        for (int q = 0; q < 8; q++) {
            acc0 = fmaf(wv[q], bf2f(h[q].x), acc0);
            acc1 = fmaf(wv[q], bf2f(h[q].y), acc1);
        }
    }
    float v0 = di * acc0;
    float v1 = di * acc1;
    if (HASBIAS) { v0 += bias[f0]; v1 += bias[f0 + 1]; }
    if (RELU) { v0 = fmaxf(v0, 0.f); v1 = fmaxf(v1, 0.f); }
    ushort2 o; o.x = f2bf(v0); o.y = f2bf(v1);
    *(ushort2*)&out[(size_t)node * F + f0] = o;
}

// fused heads aggregation: F=32 (mu 0..15, logstd 16..31), fp32 split output to d_out
template <bool USEW>
__global__ __launch_bounds__(256) void k_agg_heads(const unsigned short* __restrict__ Hb,
                                                   float* __restrict__ out,
                                                   const int* __restrict__ offs,
                                                   const uint2* __restrict__ edges,
                                                   const int* __restrict__ src,
                                                   const float* __restrict__ dinv,
                                                   const float* __restrict__ bmu, const float* __restrict__ bls,
                                                   int nnodes, int Ecap) {
    constexpr int F = 32, TPN = 16;
    int t = blockIdx.x * 256 + threadIdx.x;
    int node = t / TPN;
    int ln = t % TPN;
    if (node >= nnodes) return;
    int f0 = 2 * ln;

    float di = dinv[node];
    ushort2 sv = *(const ushort2*)&Hb[(size_t)node * F + f0];
    float acc0 = di * bf2f(sv.x);
    float acc1 = di * bf2f(sv.y);

    int s0 = offs[node];
    int s1 = offs[node + 1];
    s0 = imax(0, imin(s0, Ecap));
    s1 = imax(s0, imin(s1, Ecap));
    for (int e = s0; e < s1; e += 8) {
        int sr[8];
        float wv[8];
        if (USEW) {
            #pragma unroll
            for (int q = 0; q < 4; q++) {
                uint4 pr = *(const uint4*)(edges + e + 2 * q);
                sr[2 * q] = (int)pr.x;     wv[2 * q] = __uint_as_float(pr.y);
                sr[2 * q + 1] = (int)pr.z; wv[2 * q + 1] = __uint_as_float(pr.w);
            }
        } else {
            int4 a = *(const int4*)(src + e);
            int4 b = *(const int4*)(src + e + 4);
            sr[0] = a.x; sr[1] = a.y; sr[2] = a.z; sr[3] = a.w;
            sr[4] = b.x; sr[5] = b.y; sr[6] = b.z; sr[7] = b.w;
            #pragma unroll
            for (int q = 0; q < 8; q++) wv[q] = dinv[sr[q]];
        }
        ushort2 h[8];
        #pragma unroll
        for (int q = 0; q < 8; q++)
            h[q] = *(const ushort2*)&Hb[(size_t)sr[q] * F + f0];
        #pragma unroll
        for (int q = 0; q < 8; q++) {
            acc0 = fmaf(wv[q], bf2f(h[q].x), acc0);
            acc1 = fmaf(wv[q], bf2f(h[q].y), acc1);
        }
    }
    const float* bp = (f0 < 16) ? bmu : bls;
    int fb = f0 & 15;
    float v0 = fmaf(di, acc0, bp[fb]);
    float v1 = fmaf(di, acc1, bp[fb + 1]);
    float* op = (f0 < 16) ? (out + (size_t)node * 16 + fb)
                          : (out + (size_t)nnodes * 16 + (size_t)node * 16 + fb);
    *(float2*)op = make_float2(v0, v1);
}

// ---------------- pipeline ----------------

template <bool USEW>
static void run_pipeline(void* const* d_in, void* d_out, void* d_ws,
                         int N, int E, hipStream_t stream) {
    const float* x  = (const float*)d_in[0];
    const int* ei   = (const int*)d_in[1];
    const float* W1 = (const float*)d_in[2];
    const float* b1 = (const float*)d_in[3];
    const float* W2 = (const float*)d_in[4];
    const float* b2 = (const float*)d_in[5];
    const float* W3 = (const float*)d_in[6];
    const float* b3 = (const float*)d_in[7];
    const float* W4 = (const float*)d_in[8];
    const float* b4 = (const float*)d_in[9];
    const float* Wmu = (const float*)d_in[10];
    const float* bmu = (const float*)d_in[11];
    const float* Wls = (const float*)d_in[12];
    const float* bls = (const float*)d_in[13];
    const int* row = ei;        // edge_index[0] = source
    const int* col = ei + E;    // edge_index[1] = target
    const int nb = (N + 255) / 256;
    const int E8 = E + 8 * N;   // capacity with pad-to-8

    auto align16 = [](char* p) {
        return (char*)(((uintptr_t)p + 15) & ~(uintptr_t)15);
    };
    char* p = (char*)d_ws;
    unsigned short* act = (unsigned short*)p;    p += (size_t)N * 256 * 2;
    unsigned short* H = (unsigned short*)p;      p += (size_t)N * 256 * 2;
    unsigned short* xb = H;                      // alias (dead before H first write)
    unsigned short* xa = (unsigned short*)p;     p += (size_t)N * 128 * 2;
    float* dinv = (float*)p;                     p += (size_t)N * 4;
    int* cnt = (int*)p;                          p += (size_t)N * 4;
    int* offs = (int*)p;                         p += (size_t)(N + 1) * 4;
    int* cursor = (int*)p;                       p += (size_t)N * 4;
    int* partial = (int*)p;                      p += (size_t)N * 4;
    int* bsum = (int*)p;                         p += (size_t)nb * 4;
    int* bsumoff = (int*)p;                      p += (size_t)nb * 4;
    p = align16(p);
    unsigned short* W1T = (unsigned short*)p;    p += 256 * 128 * 2;
    unsigned short* W2T = (unsigned short*)p;    p += 128 * 256 * 2;
    unsigned short* W3T = (unsigned short*)p;    p += 64 * 128 * 2;
    p = align16(p);
    uint2* edges = nullptr;
    int* csr_src = nullptr;
    if (USEW) edges = (uint2*)p;
    else      csr_src = (int*)p;

    // prologue: zero cnt, x->bf16, weight casts (one kernel)
    {
        size_t total = (size_t)N + (size_t)N * 128 + (128 * 256 + 256 * 128 + 128 * 64);
        k_prologue<<<(unsigned)((total + 255) / 256), 256, 0, stream>>>(
            cnt, N, x, xb, (size_t)N * 128, W1, W1T, W2, W2T, W3, W3T);
    }
    // CSR + norms
    k_count<<<(E / 2 + 255) / 256, 256, 0, stream>>>(col, cnt, E, N);
    k_scan1<<<nb, 256, 0, stream>>>(cnt, partial, bsum, N);
    k_scan2<<<1, 256, 0, stream>>>(bsum, bsumoff, nb);
    k_scan3<<<nb, 256, 0, stream>>>(partial, bsumoff, cnt, offs, cursor, dinv, N);
    k_fill<USEW><<<(E / 2 + 255) / 256, 256, 0, stream>>>(row, col, cursor, dinv, edges, csr_src, E, N, E8);
    k_pad<USEW><<<nb, 256, 0, stream>>>(cnt, offs, cursor, edges, csr_src, N);

    const int gx = (N + 127) / 128;
    // layer 1: act1 = relu( (Â x) W1 + b1 )
    k_aggb<128, false, false, USEW><<<(unsigned)(((size_t)N * 64 + 255) / 256), 256, 0, stream>>>(xb, xa, offs, edges, csr_src, dinv, nullptr, N, E8);
    k_gemm_mfma<128, 256, true><<<dim3(gx, 2), 256, 0, stream>>>(xa, W1T, act, b1, N, 128);
    // layer 2
    k_gemm_mfma<128, 128, false><<<dim3(gx, 1), 256, 0, stream>>>(act, W2T, H, nullptr, N, 256);
    k_aggb<128, true, true, USEW><<<(unsigned)(((size_t)N * 64 + 255) / 256), 256, 0, stream>>>(H, act, offs, edges, csr_src, dinv, b2, N, E8);
    // layer 3
    k_gemm_mfma<64, 64, false><<<dim3(gx, 1), 256, 0, stream>>>(act, W3T, H, nullptr, N, 128);
    k_aggb<64, true, true, USEW><<<(unsigned)(((size_t)N * 32 + 255) / 256), 256, 0, stream>>>(H, act, offs, edges, csr_src, dinv, b3, N, E8);
    // layer 4
    k_gemm32<<<(N + 31) / 32, 256, 0, stream>>>(act, W4, H, N);
    k_aggb<32, true, true, USEW><<<(unsigned)(((size_t)N * 16 + 255) / 256), 256, 0, stream>>>(H, act, offs, edges, csr_src, dinv, b4, N, E8);
    // fused heads
    float* outF = (float*)d_out;
    k_gemm_heads<<<(unsigned)(((size_t)N * 32 + 255) / 256), 256, 0, stream>>>(act, Wmu, Wls, H, N);
    k_agg_heads<USEW><<<(unsigned)(((size_t)N * 16 + 255) / 256), 256, 0, stream>>>(H, outF, offs, edges, csr_src, dinv, bmu, bls, N, E8);
}

extern "C" void kernel_launch(void* const* d_in, const int* in_sizes, int n_in,
                              void* d_out, int out_size, void* d_ws, size_t ws_size,
                              hipStream_t stream) {
    const int N = in_sizes[0] / 128;
    const int E = in_sizes[1] / 2;
    const int nb = (N + 255) / 256;
    const size_t E8 = (size_t)E + 8 * (size_t)N;

    size_t fixed = (size_t)N * 256 * 2 * 2 + (size_t)N * 128 * 2
                 + (size_t)N * 4 * 5 + 4 + (size_t)nb * 8
                 + (256 * 128 + 128 * 256 + 64 * 128) * 2 + 96;
    size_t need_w = fixed + E8 * 8;
    if (ws_size >= need_w)
        run_pipeline<true>(d_in, d_out, d_ws, N, E, stream);
    else
        run_pipeline<false>(d_in, d_out, d_ws, N, E, stream);
}